// Round 2
// baseline (2956.595 us; speedup 1.0000x reference)
//
#include <hip/hip_runtime.h>

#define N_NODES 50000
#define N_EDGES 800000
#define F 128
#define NF (N_NODES * F)    // per-batch plane (50000*128)

// ---------------- degree accumulation: deg[row[e]] += attr[e] ----------------
__global__ void k_deg(const int* __restrict__ ei,
                      const float* __restrict__ attr,
                      float* __restrict__ deg) {
    int e = blockIdx.x * blockDim.x + threadIdx.x;
    if (e < N_EDGES) {
        atomicAdd(&deg[ei[e]], attr[e]);   // ei[0..E) = row indices
    }
}

// ---------------- dinv[n] = rsqrt(deg[n] + 1.0) (self-loop weight 1) --------
__global__ void k_dinv(float* __restrict__ deg) {
    int n = blockIdx.x * blockDim.x + threadIdx.x;
    if (n < N_NODES) {
        deg[n] = rsqrtf(deg[n] + 1.0f);    // deg+1 >= 1, always > 0
    }
}

// ---------------- edge scatter on RAW x: one wave per edge ------------------
// out[b,r,f] += norm * x[b,c,f]  (256 floats per edge, 4 per lane)
// s[r] += norm  (lane 0)
__global__ __launch_bounds__(256) void k_edge(const int* __restrict__ ei,
                                              const float* __restrict__ attr,
                                              const float* __restrict__ dinv,
                                              const float* __restrict__ x,
                                              float* __restrict__ out,
                                              float* __restrict__ s) {
    int e    = (int)(((size_t)blockIdx.x * 256 + threadIdx.x) >> 6);
    int lane = threadIdx.x & 63;
    if (e >= N_EDGES) return;

    int r = ei[e];
    int c = ei[N_EDGES + e];
    float norm = dinv[r] * attr[e] * dinv[c];

    if (lane == 0) atomicAdd(&s[r], norm);

    int idx = lane * 4;        // 0..252 over (b,f)
    int b = idx >> 7;          // 0 or 1
    int f = idx & 127;
    float4 v = *(const float4*)(x + (size_t)b * NF + (size_t)c * F + f);
    float* dst = out + (size_t)b * NF + (size_t)r * F + f;
    atomicAdd(dst + 0, norm * v.x);
    atomicAdd(dst + 1, norm * v.y);
    atomicAdd(dst + 2, norm * v.z);
    atomicAdd(dst + 3, norm * v.w);
}

// ---------------- fused in-place: out = relu((out + dinv^2*x) @ W^T + sfull*bias)
// 32 nodes of one batch per block; W^T staged in LDS in 2 chunks of 64 K;
// 256 threads, microtile 2 nodes x 8 outputs.
__global__ __launch_bounds__(256) void k_gemm_fused(const float* __restrict__ x,
                                                    const float* __restrict__ W,
                                                    const float* __restrict__ bias,
                                                    const float* __restrict__ dinv,
                                                    const float* __restrict__ s,
                                                    float* __restrict__ out) {
    __shared__ float sW[64 * 132];   // sW[f*132 + o] = W[o][fc*64 + f]
    __shared__ float sX[32 * 129];   // fused input rows, padded stride

    const int b   = blockIdx.y;
    const int n0  = blockIdx.x * 32;
    const int tid = threadIdx.x;

    const float* xb = x   + (size_t)b * NF;
    float*       ob = out + (size_t)b * NF;

    // stage fused rows: agg = out[b,n,:] + dinv[n]^2 * x[b,n,:]
    for (int i = 0; i < 16; ++i) {
        int idx = tid + i * 256;      // nl*128 + f
        int nl  = idx >> 7;
        int f   = idx & 127;
        int n   = n0 + nl;
        float v = 0.0f;
        if (n < N_NODES) {
            float dn = dinv[n];
            v = ob[(size_t)n * F + f] + dn * dn * xb[(size_t)n * F + f];
        }
        sX[nl * 129 + f] = v;
    }

    const int to = tid & 15;  const int o0 = to * 8;
    const int tn = tid >> 4;  const int nA = 2 * tn, nB = nA + 1;
    const int gnA = n0 + nA, gnB = n0 + nB;

    float sfA = 0.0f, sfB = 0.0f;
    if (gnA < N_NODES) { float dn = dinv[gnA]; sfA = s[gnA] + dn * dn; }
    if (gnB < N_NODES) { float dn = dinv[gnB]; sfB = s[gnB] + dn * dn; }

    float acc0[8], acc1[8];
    for (int j = 0; j < 8; ++j) {
        float bb = bias[o0 + j];
        acc0[j] = sfA * bb; acc1[j] = sfB * bb;
    }

    for (int fc = 0; fc < 2; ++fc) {
        __syncthreads();   // protects sX stores (fc==0) and prior sW reads
        for (int i = 0; i < 32; ++i) {
            int idx = tid + i * 256;  // o*64 + f'
            int o = idx >> 6;
            int f = idx & 63;
            sW[f * 132 + o] = W[o * 128 + fc * 64 + f];
        }
        __syncthreads();

        const float* sxA = &sX[nA * 129 + fc * 64];
        const float* sxB = &sX[nB * 129 + fc * 64];
        for (int f = 0; f < 64; ++f) {
            float a0 = sxA[f];
            float a1 = sxB[f];
            const float4 w0 = *(const float4*)&sW[f * 132 + o0];
            const float4 w1 = *(const float4*)&sW[f * 132 + o0 + 4];
            acc0[0] += a0 * w0.x; acc0[1] += a0 * w0.y;
            acc0[2] += a0 * w0.z; acc0[3] += a0 * w0.w;
            acc0[4] += a0 * w1.x; acc0[5] += a0 * w1.y;
            acc0[6] += a0 * w1.z; acc0[7] += a0 * w1.w;
            acc1[0] += a1 * w0.x; acc1[1] += a1 * w0.y;
            acc1[2] += a1 * w0.z; acc1[3] += a1 * w0.w;
            acc1[4] += a1 * w1.x; acc1[5] += a1 * w1.y;
            acc1[6] += a1 * w1.z; acc1[7] += a1 * w1.w;
        }
    }

    if (gnA < N_NODES) {
        float* p = &ob[(size_t)gnA * F + o0];
        *(float4*)(p)     = make_float4(fmaxf(acc0[0],0.f), fmaxf(acc0[1],0.f),
                                        fmaxf(acc0[2],0.f), fmaxf(acc0[3],0.f));
        *(float4*)(p + 4) = make_float4(fmaxf(acc0[4],0.f), fmaxf(acc0[5],0.f),
                                        fmaxf(acc0[6],0.f), fmaxf(acc0[7],0.f));
    }
    if (gnB < N_NODES) {
        float* p = &ob[(size_t)gnB * F + o0];
        *(float4*)(p)     = make_float4(fmaxf(acc1[0],0.f), fmaxf(acc1[1],0.f),
                                        fmaxf(acc1[2],0.f), fmaxf(acc1[3],0.f));
        *(float4*)(p + 4) = make_float4(fmaxf(acc1[4],0.f), fmaxf(acc1[5],0.f),
                                        fmaxf(acc1[6],0.f), fmaxf(acc1[7],0.f));
    }
}

extern "C" void kernel_launch(void* const* d_in, const int* in_sizes, int n_in,
                              void* d_out, int out_size, void* d_ws, size_t ws_size,
                              hipStream_t stream) {
    const float* x    = (const float*)d_in[0];    // [2, 50000, 128] f32
    const int*   ei   = (const int*)d_in[1];      // [2, 800000] int32 (harness: integer -> int*)
    const float* attr = (const float*)d_in[2];    // [800000, 1] f32
    const float* W    = (const float*)d_in[3];    // [128, 128] f32
    const float* bias = (const float*)d_in[4];    // [128] f32
    float* out = (float*)d_out;                   // [2, 50000, 128] f32

    // ws layout: deg/dinv [N] | s [N]  — 400 KB total
    float* deg = (float*)d_ws;
    float* s   = deg + N_NODES;

    hipMemsetAsync(deg, 0, 2 * N_NODES * sizeof(float), stream);   // deg + s
    hipMemsetAsync(out, 0, (size_t)2 * NF * sizeof(float), stream);

    k_deg<<<(N_EDGES + 255) / 256, 256, 0, stream>>>(ei, attr, deg);
    k_dinv<<<(N_NODES + 255) / 256, 256, 0, stream>>>(deg);

    // one wave (64 lanes) per edge
    size_t edge_threads = (size_t)N_EDGES * 64;
    k_edge<<<(unsigned)((edge_threads + 255) / 256), 256, 0, stream>>>(ei, attr, deg, x, out, s);

    dim3 gg((N_NODES + 31) / 32, 2);
    k_gemm_fused<<<gg, 256, 0, stream>>>(x, W, bias, deg, s, out);
}

// Round 3
// 424.155 us; speedup vs baseline: 6.9706x; 6.9706x over previous
//
#include <hip/hip_runtime.h>

#define N_NODES 50000
#define N_EDGES 800000
#define F 128
#define NF (N_NODES * F)        // per-batch plane
#define SCAN_BLOCKS ((N_NODES + 255) / 256)   // 196

// ================= common: degree + count ===================================
__global__ void k_deg_cnt(const int* __restrict__ ei,
                          const float* __restrict__ attr,
                          float* __restrict__ deg,
                          int* __restrict__ cnt) {
    int e = blockIdx.x * blockDim.x + threadIdx.x;
    if (e < N_EDGES) {
        int r = ei[e];
        atomicAdd(&deg[r], attr[e]);
        atomicAdd(&cnt[r], 1);
    }
}

__global__ void k_dinv(float* __restrict__ deg) {
    int n = blockIdx.x * blockDim.x + threadIdx.x;
    if (n < N_NODES) deg[n] = rsqrtf(deg[n] + 1.0f);   // self-loop weight 1
}

// ================= exclusive scan of cnt -> rowstart ========================
__global__ __launch_bounds__(256) void k_scan1(const int* __restrict__ cnt,
                                               int* __restrict__ rowstart,
                                               int* __restrict__ partials) {
    __shared__ int tmp[256];
    int i = blockIdx.x * 256 + threadIdx.x;
    int v = (i < N_NODES) ? cnt[i] : 0;
    tmp[threadIdx.x] = v;
    __syncthreads();
    for (int off = 1; off < 256; off <<= 1) {
        int t = (threadIdx.x >= off) ? tmp[threadIdx.x - off] : 0;
        __syncthreads();
        tmp[threadIdx.x] += t;
        __syncthreads();
    }
    if (i < N_NODES) rowstart[i] = tmp[threadIdx.x] - v;   // exclusive in block
    if (threadIdx.x == 255) partials[blockIdx.x] = tmp[255];
}

__global__ __launch_bounds__(256) void k_scan2(int* __restrict__ partials) {
    __shared__ int tmp[256];
    int v = (threadIdx.x < SCAN_BLOCKS) ? partials[threadIdx.x] : 0;
    tmp[threadIdx.x] = v;
    __syncthreads();
    for (int off = 1; off < 256; off <<= 1) {
        int t = (threadIdx.x >= off) ? tmp[threadIdx.x - off] : 0;
        __syncthreads();
        tmp[threadIdx.x] += t;
        __syncthreads();
    }
    if (threadIdx.x < SCAN_BLOCKS) partials[threadIdx.x] = tmp[threadIdx.x] - v;
}

__global__ void k_scan3(int* __restrict__ rowstart, const int* __restrict__ partials) {
    int i = blockIdx.x * blockDim.x + threadIdx.x;
    if (i < N_NODES) rowstart[i] += partials[i >> 8];
    if (i == 0) rowstart[N_NODES] = N_EDGES;
}

// ================= fill sorted (col, norm) per dest row =====================
__global__ void k_fill(const int* __restrict__ ei,
                       const float* __restrict__ attr,
                       const float* __restrict__ dinv,
                       const int* __restrict__ rowstart,
                       int* __restrict__ cnt,           // consumed to 0
                       uint2* __restrict__ sorted) {
    int e = blockIdx.x * blockDim.x + threadIdx.x;
    if (e >= N_EDGES) return;
    int r = ei[e];
    int c = ei[N_EDGES + e];
    float norm = dinv[r] * attr[e] * dinv[c];
    int slot = atomicSub(&cnt[r], 1) - 1;          // unique 0..count-1
    sorted[rowstart[r] + slot] = make_uint2((unsigned)c, __float_as_uint(norm));
}

// ================= gather: one wave per dest row ============================
// out[b,r,f] = sum_e norm_e * x[b,c_e,f];  s[r] = sum_e norm_e
__global__ __launch_bounds__(256) void k_gather(const int* __restrict__ rowstart,
                                                const uint2* __restrict__ sorted,
                                                const float* __restrict__ x,
                                                float* __restrict__ out,
                                                float* __restrict__ s) {
    int r    = (int)(((size_t)blockIdx.x * 256 + threadIdx.x) >> 6);
    int lane = threadIdx.x & 63;
    if (r >= N_NODES) return;

    int start = rowstart[r];
    int end   = rowstart[r + 1];

    int idx = lane * 4;            // 0..252 over (b,f)
    int b = idx >> 7;
    int f = idx & 127;
    const float* xbf = x + (size_t)b * NF + f;

    float4 acc = make_float4(0.f, 0.f, 0.f, 0.f);
    float snorm = 0.0f;

    for (int base = start; base < end; base += 64) {
        int m = end - base; if (m > 64) m = 64;
        uint2 en = make_uint2(0u, 0u);
        if (base + lane < end) en = sorted[base + lane];   // coalesced 8B/lane
        int   ec = (int)en.x;
        float ew = __uint_as_float(en.y);
        for (int j = 0; j < m; ++j) {
            int   c  = __shfl(ec, j);
            float nm = __shfl(ew, j);
            const float4 v = *(const float4*)(xbf + (size_t)c * F);
            acc.x += nm * v.x; acc.y += nm * v.y;
            acc.z += nm * v.z; acc.w += nm * v.w;
            snorm += nm;
        }
    }

    *(float4*)(out + (size_t)b * NF + (size_t)r * F + f) = acc;
    if (lane == 0) s[r] = snorm;
}

// ================= fallback atomic scatter (small ws only) ==================
__global__ __launch_bounds__(256) void k_edge(const int* __restrict__ ei,
                                              const float* __restrict__ attr,
                                              const float* __restrict__ dinv,
                                              const float* __restrict__ x,
                                              float* __restrict__ out,
                                              float* __restrict__ s) {
    int e    = (int)(((size_t)blockIdx.x * 256 + threadIdx.x) >> 6);
    int lane = threadIdx.x & 63;
    if (e >= N_EDGES) return;
    int r = ei[e];
    int c = ei[N_EDGES + e];
    float norm = dinv[r] * attr[e] * dinv[c];
    if (lane == 0) atomicAdd(&s[r], norm);
    int idx = lane * 4;
    int b = idx >> 7;
    int f = idx & 127;
    float4 v = *(const float4*)(x + (size_t)b * NF + (size_t)c * F + f);
    float* dst = out + (size_t)b * NF + (size_t)r * F + f;
    atomicAdd(dst + 0, norm * v.x);
    atomicAdd(dst + 1, norm * v.y);
    atomicAdd(dst + 2, norm * v.z);
    atomicAdd(dst + 3, norm * v.w);
}

// ================= fused in-place GEMM epilogue =============================
// out = relu((out + dinv^2*x) @ W^T + (s + dinv^2)*bias)
__global__ __launch_bounds__(256) void k_gemm_fused(const float* __restrict__ x,
                                                    const float* __restrict__ W,
                                                    const float* __restrict__ bias,
                                                    const float* __restrict__ dinv,
                                                    const float* __restrict__ s,
                                                    float* __restrict__ out) {
    __shared__ float sW[64 * 132];
    __shared__ float sX[32 * 129];

    const int b   = blockIdx.y;
    const int n0  = blockIdx.x * 32;
    const int tid = threadIdx.x;

    const float* xb = x   + (size_t)b * NF;
    float*       ob = out + (size_t)b * NF;

    for (int i = 0; i < 16; ++i) {
        int idx = tid + i * 256;
        int nl  = idx >> 7;
        int f   = idx & 127;
        int n   = n0 + nl;
        float v = 0.0f;
        if (n < N_NODES) {
            float dn = dinv[n];
            v = ob[(size_t)n * F + f] + dn * dn * xb[(size_t)n * F + f];
        }
        sX[nl * 129 + f] = v;
    }

    const int to = tid & 15;  const int o0 = to * 8;
    const int tn = tid >> 4;  const int nA = 2 * tn, nB = nA + 1;
    const int gnA = n0 + nA, gnB = n0 + nB;

    float sfA = 0.0f, sfB = 0.0f;
    if (gnA < N_NODES) { float dn = dinv[gnA]; sfA = s[gnA] + dn * dn; }
    if (gnB < N_NODES) { float dn = dinv[gnB]; sfB = s[gnB] + dn * dn; }

    float acc0[8], acc1[8];
    for (int j = 0; j < 8; ++j) {
        float bb = bias[o0 + j];
        acc0[j] = sfA * bb; acc1[j] = sfB * bb;
    }

    for (int fc = 0; fc < 2; ++fc) {
        __syncthreads();
        for (int i = 0; i < 32; ++i) {
            int idx = tid + i * 256;
            int o = idx >> 6;
            int f = idx & 63;
            sW[f * 132 + o] = W[o * 128 + fc * 64 + f];
        }
        __syncthreads();

        const float* sxA = &sX[nA * 129 + fc * 64];
        const float* sxB = &sX[nB * 129 + fc * 64];
        for (int f = 0; f < 64; ++f) {
            float a0 = sxA[f];
            float a1 = sxB[f];
            const float4 w0 = *(const float4*)&sW[f * 132 + o0];
            const float4 w1 = *(const float4*)&sW[f * 132 + o0 + 4];
            acc0[0] += a0 * w0.x; acc0[1] += a0 * w0.y;
            acc0[2] += a0 * w0.z; acc0[3] += a0 * w0.w;
            acc0[4] += a0 * w1.x; acc0[5] += a0 * w1.y;
            acc0[6] += a0 * w1.z; acc0[7] += a0 * w1.w;
            acc1[0] += a1 * w0.x; acc1[1] += a1 * w0.y;
            acc1[2] += a1 * w0.z; acc1[3] += a1 * w0.w;
            acc1[4] += a1 * w1.x; acc1[5] += a1 * w1.y;
            acc1[6] += a1 * w1.z; acc1[7] += a1 * w1.w;
        }
    }

    if (gnA < N_NODES) {
        float* p = &ob[(size_t)gnA * F + o0];
        *(float4*)(p)     = make_float4(fmaxf(acc0[0],0.f), fmaxf(acc0[1],0.f),
                                        fmaxf(acc0[2],0.f), fmaxf(acc0[3],0.f));
        *(float4*)(p + 4) = make_float4(fmaxf(acc0[4],0.f), fmaxf(acc0[5],0.f),
                                        fmaxf(acc0[6],0.f), fmaxf(acc0[7],0.f));
    }
    if (gnB < N_NODES) {
        float* p = &ob[(size_t)gnB * F + o0];
        *(float4*)(p)     = make_float4(fmaxf(acc1[0],0.f), fmaxf(acc1[1],0.f),
                                        fmaxf(acc1[2],0.f), fmaxf(acc1[3],0.f));
        *(float4*)(p + 4) = make_float4(fmaxf(acc1[4],0.f), fmaxf(acc1[5],0.f),
                                        fmaxf(acc1[6],0.f), fmaxf(acc1[7],0.f));
    }
}

extern "C" void kernel_launch(void* const* d_in, const int* in_sizes, int n_in,
                              void* d_out, int out_size, void* d_ws, size_t ws_size,
                              hipStream_t stream) {
    const float* x    = (const float*)d_in[0];    // [2, 50000, 128] f32
    const int*   ei   = (const int*)d_in[1];      // [2, 800000] int32
    const float* attr = (const float*)d_in[2];    // [800000, 1] f32
    const float* W    = (const float*)d_in[3];    // [128, 128] f32
    const float* bias = (const float*)d_in[4];    // [128] f32
    float* out = (float*)d_out;                   // [2, 50000, 128] f32

    // ws layout (4B units): deg[N] | s[N] | cnt[N] | rowstart[N+1] | partials[256] | pad | sorted[E]*8B
    float* deg      = (float*)d_ws;
    float* s        = deg + N_NODES;
    int*   cnt      = (int*)(s + N_NODES);
    int*   rowstart = cnt + N_NODES;
    int*   partials = rowstart + N_NODES + 1;
    size_t sorted_off = ((size_t)((char*)(partials + 256) - (char*)d_ws) + 7) & ~(size_t)7;
    uint2* sorted   = (uint2*)((char*)d_ws + sorted_off);
    size_t needed   = sorted_off + (size_t)N_EDGES * 8;

    if (ws_size >= needed) {
        // -------- CSR counting-sort path (no feature atomics) --------
        hipMemsetAsync(deg, 0, N_NODES * sizeof(float), stream);
        hipMemsetAsync(cnt, 0, N_NODES * sizeof(int), stream);

        k_deg_cnt<<<(N_EDGES + 255) / 256, 256, 0, stream>>>(ei, attr, deg, cnt);
        k_dinv<<<(N_NODES + 255) / 256, 256, 0, stream>>>(deg);

        k_scan1<<<SCAN_BLOCKS, 256, 0, stream>>>(cnt, rowstart, partials);
        k_scan2<<<1, 256, 0, stream>>>(partials);
        k_scan3<<<SCAN_BLOCKS, 256, 0, stream>>>(rowstart, partials);

        k_fill<<<(N_EDGES + 255) / 256, 256, 0, stream>>>(ei, attr, deg, rowstart, cnt, sorted);

        size_t gthreads = (size_t)N_NODES * 64;
        k_gather<<<(unsigned)((gthreads + 255) / 256), 256, 0, stream>>>(rowstart, sorted, x, out, s);
    } else {
        // -------- fallback: atomic scatter --------
        hipMemsetAsync(deg, 0, 2 * N_NODES * sizeof(float), stream);  // deg + s
        hipMemsetAsync(out, 0, (size_t)2 * NF * sizeof(float), stream);
        int* dummy_cnt = (int*)(s + N_NODES);  // unused writes ok if within ws? keep safe:
        (void)dummy_cnt;
        k_deg_cnt<<<(N_EDGES + 255) / 256, 256, 0, stream>>>(ei, attr, deg, (int*)s); // cnt aliased to s, unused later
        k_dinv<<<(N_NODES + 255) / 256, 256, 0, stream>>>(deg);
        hipMemsetAsync(s, 0, N_NODES * sizeof(float), stream);        // re-zero s after alias abuse
        size_t edge_threads = (size_t)N_EDGES * 64;
        k_edge<<<(unsigned)((edge_threads + 255) / 256), 256, 0, stream>>>(ei, attr, deg, x, out, s);
    }

    dim3 gg((N_NODES + 31) / 32, 2);
    k_gemm_fused<<<gg, 256, 0, stream>>>(x, W, bias, deg, s, out);
}

// Round 4
// 349.148 us; speedup vs baseline: 8.4680x; 1.2148x over previous
//
#include <hip/hip_runtime.h>

#define N_NODES 50000
#define N_EDGES 800000
#define F 128
#define BF 256
#define NF (N_NODES * F)
#define SCAN_BLOCKS ((N_NODES + 255) / 256)   // 196

typedef __attribute__((ext_vector_type(8))) _Float16 half8;
typedef __attribute__((ext_vector_type(4))) _Float16 half4;
typedef __attribute__((ext_vector_type(4))) float floatx4;

// ================= degree + count ===========================================
__global__ void k_deg_cnt(const int* __restrict__ ei,
                          const float* __restrict__ attr,
                          float* __restrict__ deg,
                          int* __restrict__ cnt) {
    int e = blockIdx.x * blockDim.x + threadIdx.x;
    if (e < N_EDGES) {
        int r = ei[e];
        atomicAdd(&deg[r], attr[e]);
        atomicAdd(&cnt[r], 1);
    }
}

__global__ void k_dinv(float* __restrict__ deg) {
    int n = blockIdx.x * blockDim.x + threadIdx.x;
    if (n < N_NODES) deg[n] = rsqrtf(deg[n] + 1.0f);   // self-loop weight 1
}

// ================= exclusive scan of cnt -> rowstart ========================
__global__ __launch_bounds__(256) void k_scan1(const int* __restrict__ cnt,
                                               int* __restrict__ rowstart,
                                               int* __restrict__ partials) {
    __shared__ int tmp[256];
    int i = blockIdx.x * 256 + threadIdx.x;
    int v = (i < N_NODES) ? cnt[i] : 0;
    tmp[threadIdx.x] = v;
    __syncthreads();
    for (int off = 1; off < 256; off <<= 1) {
        int t = (threadIdx.x >= off) ? tmp[threadIdx.x - off] : 0;
        __syncthreads();
        tmp[threadIdx.x] += t;
        __syncthreads();
    }
    if (i < N_NODES) rowstart[i] = tmp[threadIdx.x] - v;
    if (threadIdx.x == 255) partials[blockIdx.x] = tmp[255];
}

__global__ __launch_bounds__(256) void k_scan2(int* __restrict__ partials) {
    __shared__ int tmp[256];
    int v = (threadIdx.x < SCAN_BLOCKS) ? partials[threadIdx.x] : 0;
    tmp[threadIdx.x] = v;
    __syncthreads();
    for (int off = 1; off < 256; off <<= 1) {
        int t = (threadIdx.x >= off) ? tmp[threadIdx.x - off] : 0;
        __syncthreads();
        tmp[threadIdx.x] += t;
        __syncthreads();
    }
    if (threadIdx.x < SCAN_BLOCKS) partials[threadIdx.x] = tmp[threadIdx.x] - v;
}

__global__ void k_scan3(int* __restrict__ rowstart, const int* __restrict__ partials) {
    int i = blockIdx.x * blockDim.x + threadIdx.x;
    if (i < N_NODES) rowstart[i] += partials[i >> 8];
    if (i == 0) rowstart[N_NODES] = N_EDGES;
}

// ================= fill sorted (col, norm) per dest row =====================
__global__ void k_fill(const int* __restrict__ ei,
                       const float* __restrict__ attr,
                       const float* __restrict__ dinv,
                       const int* __restrict__ rowstart,
                       int* __restrict__ cnt,
                       uint2* __restrict__ sorted) {
    int e = blockIdx.x * blockDim.x + threadIdx.x;
    if (e >= N_EDGES) return;
    int r = ei[e];
    int c = ei[N_EDGES + e];
    float norm = dinv[r] * attr[e] * dinv[c];
    int slot = atomicSub(&cnt[r], 1) - 1;
    sorted[rowstart[r] + slot] = make_uint2((unsigned)c, __float_as_uint(norm));
}

// ================= convert x -> interleaved fp16 xi[n][b*128+f] =============
__global__ void k_cvt(const float* __restrict__ x, _Float16* __restrict__ xi) {
    int i = blockIdx.x * 256 + threadIdx.x;       // float4 index
    if (i >= 2 * NF / 4) return;
    size_t base = (size_t)i * 4;
    int b = (base >= (size_t)NF) ? 1 : 0;
    size_t rem = base - (size_t)b * NF;
    int n = (int)(rem >> 7);
    int f = (int)(rem & 127);
    float4 v = *(const float4*)(x + base);
    half4 h;
    h[0] = (_Float16)v.x; h[1] = (_Float16)v.y;
    h[2] = (_Float16)v.z; h[3] = (_Float16)v.w;
    *(half4*)(xi + (size_t)n * BF + b * F + f) = h;
}

// ================= gather (fp16 source): one wave per dest row ==============
// out[b,r,f] = dinv[r]^2*x[b,r,f] + sum_e norm_e * x[b,c_e,f];  s[r] = full sum
__global__ __launch_bounds__(256) void k_gather_h(const int* __restrict__ rowstart,
                                                  const uint2* __restrict__ sorted,
                                                  const _Float16* __restrict__ xi,
                                                  const float* __restrict__ dinv,
                                                  float* __restrict__ out,
                                                  float* __restrict__ s) {
    int r    = (int)(((size_t)blockIdx.x * 256 + threadIdx.x) >> 6);
    int lane = threadIdx.x & 63;
    if (r >= N_NODES) return;

    int start = rowstart[r];
    int end   = rowstart[r + 1];

    int idx = lane * 4;            // 0..252 over (b,f)
    int b = idx >> 7;
    int f = idx & 127;

    float dn  = dinv[r];
    float nm0 = dn * dn;
    half4 hv  = *(const half4*)(xi + (size_t)r * BF + idx);
    float4 acc = make_float4(nm0 * (float)hv[0], nm0 * (float)hv[1],
                             nm0 * (float)hv[2], nm0 * (float)hv[3]);
    float snorm = nm0;

    for (int base = start; base < end; base += 64) {
        int m = end - base; if (m > 64) m = 64;
        uint2 en = make_uint2(0u, 0u);
        if (base + lane < end) en = sorted[base + lane];
        int   ec = (int)en.x;
        float ew = __uint_as_float(en.y);
        for (int j = 0; j < m; ++j) {
            int   c  = __shfl(ec, j);
            float nm = __shfl(ew, j);
            half4 v = *(const half4*)(xi + (size_t)c * BF + idx);
            acc.x += nm * (float)v[0]; acc.y += nm * (float)v[1];
            acc.z += nm * (float)v[2]; acc.w += nm * (float)v[3];
            snorm += nm;
        }
    }

    *(float4*)(out + (size_t)b * NF + (size_t)r * F + f) = acc;
    if (lane == 0) s[r] = snorm;
}

// ================= gather (fp32 source) fallback ============================
__global__ __launch_bounds__(256) void k_gather_f(const int* __restrict__ rowstart,
                                                  const uint2* __restrict__ sorted,
                                                  const float* __restrict__ x,
                                                  const float* __restrict__ dinv,
                                                  float* __restrict__ out,
                                                  float* __restrict__ s) {
    int r    = (int)(((size_t)blockIdx.x * 256 + threadIdx.x) >> 6);
    int lane = threadIdx.x & 63;
    if (r >= N_NODES) return;

    int start = rowstart[r];
    int end   = rowstart[r + 1];

    int idx = lane * 4;
    int b = idx >> 7;
    int f = idx & 127;
    const float* xbf = x + (size_t)b * NF + f;

    float dn  = dinv[r];
    float nm0 = dn * dn;
    float4 v0 = *(const float4*)(xbf + (size_t)r * F);
    float4 acc = make_float4(nm0 * v0.x, nm0 * v0.y, nm0 * v0.z, nm0 * v0.w);
    float snorm = nm0;

    for (int base = start; base < end; base += 64) {
        int m = end - base; if (m > 64) m = 64;
        uint2 en = make_uint2(0u, 0u);
        if (base + lane < end) en = sorted[base + lane];
        int   ec = (int)en.x;
        float ew = __uint_as_float(en.y);
        for (int j = 0; j < m; ++j) {
            int   c  = __shfl(ec, j);
            float nm = __shfl(ew, j);
            const float4 v = *(const float4*)(xbf + (size_t)c * F);
            acc.x += nm * v.x; acc.y += nm * v.y;
            acc.z += nm * v.z; acc.w += nm * v.w;
            snorm += nm;
        }
    }

    *(float4*)(out + (size_t)b * NF + (size_t)r * F + f) = acc;
    if (lane == 0) s[r] = snorm;
}

// ================= atomic fallback pieces (tiny ws only) ====================
__global__ __launch_bounds__(256) void k_edge(const int* __restrict__ ei,
                                              const float* __restrict__ attr,
                                              const float* __restrict__ dinv,
                                              const float* __restrict__ x,
                                              float* __restrict__ out,
                                              float* __restrict__ s) {
    int e    = (int)(((size_t)blockIdx.x * 256 + threadIdx.x) >> 6);
    int lane = threadIdx.x & 63;
    if (e >= N_EDGES) return;
    int r = ei[e];
    int c = ei[N_EDGES + e];
    float norm = dinv[r] * attr[e] * dinv[c];
    if (lane == 0) atomicAdd(&s[r], norm);
    int idx = lane * 4;
    int b = idx >> 7;
    int f = idx & 127;
    float4 v = *(const float4*)(x + (size_t)b * NF + (size_t)c * F + f);
    float* dst = out + (size_t)b * NF + (size_t)r * F + f;
    atomicAdd(dst + 0, norm * v.x);
    atomicAdd(dst + 1, norm * v.y);
    atomicAdd(dst + 2, norm * v.z);
    atomicAdd(dst + 3, norm * v.w);
}

__global__ void k_self(const float* __restrict__ x, const float* __restrict__ dinv,
                       float* __restrict__ out) {
    int i = blockIdx.x * 256 + threadIdx.x;
    if (i >= 2 * NF / 4) return;
    size_t base = (size_t)i * 4;
    int b = (base >= (size_t)NF) ? 1 : 0;
    size_t rem = base - (size_t)b * NF;
    int n = (int)(rem >> 7);
    float dn = dinv[n]; float sc = dn * dn;
    float4 v = *(const float4*)(x + base);
    float4* op = (float4*)(out + base);
    float4 o = *op;
    o.x += sc * v.x; o.y += sc * v.y; o.z += sc * v.z; o.w += sc * v.w;
    *op = o;
}

__global__ void k_sfix(const float* __restrict__ dinv, float* __restrict__ s) {
    int n = blockIdx.x * blockDim.x + threadIdx.x;
    if (n < N_NODES) { float dn = dinv[n]; s[n] += dn * dn; }
}

// ================= MFMA GEMM epilogue (in-place on out) =====================
// out[b,n,:] = relu( fp16(out[b,n,:]) @ fp16(W)^T + s[n]*bias )
__global__ __launch_bounds__(256) void k_gemm(const float* __restrict__ W,
                                              const float* __restrict__ bias,
                                              const float* __restrict__ s,
                                              float* __restrict__ out) {
    __shared__ _Float16 sW[128 * 136];   // sW[o*136 + k], pad 8 halfs -> 2-way-free banks
    __shared__ _Float16 sA[64 * 136];    // sA[nl*136 + k]

    const int tid = threadIdx.x;
    const int b   = blockIdx.y;
    const int n0  = blockIdx.x * 64;
    float* ob = out + (size_t)b * NF;

    // stage W -> fp16 LDS (coalesced)
    for (int i = 0; i < 64; ++i) {
        int idx = i * 256 + tid;
        sW[(idx >> 7) * 136 + (idx & 127)] = (_Float16)W[idx];
    }
    // stage A rows (the aggregated out) -> fp16 LDS
    for (int i = 0; i < 32; ++i) {
        int idx = i * 256 + tid;
        int nl = idx >> 7, k = idx & 127;
        int n = n0 + nl;
        sA[nl * 136 + k] = (n < N_NODES) ? (_Float16)ob[(size_t)n * F + k] : (_Float16)0.0f;
    }
    __syncthreads();

    const int wave = tid >> 6, lane = tid & 63;
    const int ln = lane & 15, quad = lane >> 4;
    const int nw = wave * 16;                 // strip offset in tile
    if (n0 + nw >= N_NODES) return;           // N_NODES % 16 == 0, whole strip valid/invalid

    floatx4 acc[8];
    for (int ot = 0; ot < 8; ++ot) acc[ot] = (floatx4){0.f, 0.f, 0.f, 0.f};

    for (int k0 = 0; k0 < 4; ++k0) {
        half8 a = *(const half8*)&sA[(nw + ln) * 136 + k0 * 32 + quad * 8];
        for (int ot = 0; ot < 8; ++ot) {
            half8 bf = *(const half8*)&sW[(ot * 16 + ln) * 136 + k0 * 32 + quad * 8];
            acc[ot] = __builtin_amdgcn_mfma_f32_16x16x32_f16(a, bf, acc[ot], 0, 0, 0);
        }
    }

    // epilogue: D[row=quad*4+reg][col=lane&15] ; add s*bias, relu, store
    float sv[4];
    for (int rg = 0; rg < 4; ++rg) sv[rg] = s[n0 + nw + quad * 4 + rg];
    for (int ot = 0; ot < 8; ++ot) {
        int o = ot * 16 + ln;
        float bo = bias[o];
        for (int rg = 0; rg < 4; ++rg) {
            int n = n0 + nw + quad * 4 + rg;
            float v = acc[ot][rg] + sv[rg] * bo;
            ob[(size_t)n * F + o] = fmaxf(v, 0.0f);
        }
    }
}

extern "C" void kernel_launch(void* const* d_in, const int* in_sizes, int n_in,
                              void* d_out, int out_size, void* d_ws, size_t ws_size,
                              hipStream_t stream) {
    const float* x    = (const float*)d_in[0];
    const int*   ei   = (const int*)d_in[1];
    const float* attr = (const float*)d_in[2];
    const float* W    = (const float*)d_in[3];
    const float* bias = (const float*)d_in[4];
    float* out = (float*)d_out;

    // ws layout: deg[N] | s[N] | cnt[N] | rowstart[N+1] | partials[256] | pad | sorted[E] | xi[2*NF] fp16
    float* deg      = (float*)d_ws;
    float* s        = deg + N_NODES;
    int*   cnt      = (int*)(s + N_NODES);
    int*   rowstart = cnt + N_NODES;
    int*   partials = rowstart + N_NODES + 1;
    size_t sorted_off = ((size_t)((char*)(partials + 256) - (char*)d_ws) + 15) & ~(size_t)15;
    uint2* sorted   = (uint2*)((char*)d_ws + sorted_off);
    size_t xi_off   = sorted_off + (size_t)N_EDGES * 8;
    _Float16* xi    = (_Float16*)((char*)d_ws + xi_off);
    size_t need_csr  = xi_off;
    size_t need_full = xi_off + (size_t)2 * NF * 2;

    if (ws_size >= need_csr) {
        hipMemsetAsync(deg, 0, N_NODES * sizeof(float), stream);
        hipMemsetAsync(cnt, 0, N_NODES * sizeof(int), stream);

        k_deg_cnt<<<(N_EDGES + 255) / 256, 256, 0, stream>>>(ei, attr, deg, cnt);
        k_dinv<<<(N_NODES + 255) / 256, 256, 0, stream>>>(deg);

        k_scan1<<<SCAN_BLOCKS, 256, 0, stream>>>(cnt, rowstart, partials);
        k_scan2<<<1, 256, 0, stream>>>(partials);
        k_scan3<<<SCAN_BLOCKS, 256, 0, stream>>>(rowstart, partials);

        k_fill<<<(N_EDGES + 255) / 256, 256, 0, stream>>>(ei, attr, deg, rowstart, cnt, sorted);

        size_t gthreads = (size_t)N_NODES * 64;
        if (ws_size >= need_full) {
            k_cvt<<<(2 * NF / 4 + 255) / 256, 256, 0, stream>>>(x, xi);
            k_gather_h<<<(unsigned)((gthreads + 255) / 256), 256, 0, stream>>>(
                rowstart, sorted, xi, deg, out, s);
        } else {
            k_gather_f<<<(unsigned)((gthreads + 255) / 256), 256, 0, stream>>>(
                rowstart, sorted, x, deg, out, s);
        }
    } else {
        // atomic fallback (needs only deg+s = 400 KB)
        hipMemsetAsync(deg, 0, 2 * N_NODES * sizeof(float), stream);
        hipMemsetAsync(out, 0, (size_t)2 * NF * sizeof(float), stream);
        k_deg_cnt<<<(N_EDGES + 255) / 256, 256, 0, stream>>>(ei, attr, deg, (int*)s);
        k_dinv<<<(N_NODES + 255) / 256, 256, 0, stream>>>(deg);
        hipMemsetAsync(s, 0, N_NODES * sizeof(float), stream);
        size_t edge_threads = (size_t)N_EDGES * 64;
        k_edge<<<(unsigned)((edge_threads + 255) / 256), 256, 0, stream>>>(ei, attr, deg, x, out, s);
        k_self<<<(2 * NF / 4 + 255) / 256, 256, 0, stream>>>(x, deg, out);
        k_sfix<<<(N_NODES + 255) / 256, 256, 0, stream>>>(deg, s);
    }

    dim3 gg((N_NODES + 63) / 64, 2);
    k_gemm<<<gg, 256, 0, stream>>>(W, bias, deg, out);
}

// Round 5
// 304.422 us; speedup vs baseline: 9.7121x; 1.1469x over previous
//
#include <hip/hip_runtime.h>

#define N_NODES 50000
#define N_EDGES 800000
#define F 128
#define BF 256
#define NF (N_NODES * F)
#define SCAN_BLOCKS ((N_NODES + 255) / 256)   // 196
#define PRE_BLOCKS 3200
#define PRE_THREADS (PRE_BLOCKS * 256)        // 819200

typedef __attribute__((ext_vector_type(8))) _Float16 half8;
typedef __attribute__((ext_vector_type(4))) _Float16 half4;
typedef __attribute__((ext_vector_type(4))) float floatx4;

// ========== pre: edge degree/count atomics + x -> fp16 interleaved ==========
__global__ __launch_bounds__(256) void k_pre(const int* __restrict__ ei,
                                             const float* __restrict__ attr,
                                             const float* __restrict__ x,
                                             float* __restrict__ deg,
                                             int* __restrict__ cnt,
                                             _Float16* __restrict__ xi,
                                             int do_cvt) {
    int t = blockIdx.x * 256 + threadIdx.x;
    if (t < N_EDGES) {
        int r = ei[t];
        atomicAdd(&deg[r], attr[t]);
        atomicAdd(&cnt[r], 1);
    }
    if (do_cvt) {
        for (int i = t; i < 2 * NF / 4; i += PRE_THREADS) {
            size_t base = (size_t)i * 4;
            int b = (base >= (size_t)NF) ? 1 : 0;
            size_t rem = base - (size_t)b * NF;
            int n = (int)(rem >> 7);
            int f = (int)(rem & 127);
            float4 v = *(const float4*)(x + base);
            half4 h;
            h[0] = (_Float16)v.x; h[1] = (_Float16)v.y;
            h[2] = (_Float16)v.z; h[3] = (_Float16)v.w;
            *(half4*)(xi + (size_t)n * BF + b * F + f) = h;
        }
    }
}

// ========== scan1: dinv fold + per-block exclusive scan of cnt ==============
__global__ __launch_bounds__(256) void k_scan1(float* __restrict__ deg,
                                               const int* __restrict__ cnt,
                                               int* __restrict__ rowstart,
                                               int* __restrict__ partials) {
    __shared__ int tmp[256];
    int i = blockIdx.x * 256 + threadIdx.x;
    if (i < N_NODES) deg[i] = rsqrtf(deg[i] + 1.0f);   // dinv in place
    int v = (i < N_NODES) ? cnt[i] : 0;
    tmp[threadIdx.x] = v;
    __syncthreads();
    for (int off = 1; off < 256; off <<= 1) {
        int t = (threadIdx.x >= off) ? tmp[threadIdx.x - off] : 0;
        __syncthreads();
        tmp[threadIdx.x] += t;
        __syncthreads();
    }
    if (i < N_NODES) rowstart[i] = tmp[threadIdx.x] - v;   // block-local exclusive
    if (threadIdx.x == 255) partials[blockIdx.x] = tmp[255];
}

__global__ __launch_bounds__(256) void k_scan2(int* __restrict__ partials) {
    __shared__ int tmp[256];
    int v = (threadIdx.x < SCAN_BLOCKS) ? partials[threadIdx.x] : 0;
    tmp[threadIdx.x] = v;
    __syncthreads();
    for (int off = 1; off < 256; off <<= 1) {
        int t = (threadIdx.x >= off) ? tmp[threadIdx.x - off] : 0;
        __syncthreads();
        tmp[threadIdx.x] += t;
        __syncthreads();
    }
    if (threadIdx.x < SCAN_BLOCKS) partials[threadIdx.x] = tmp[threadIdx.x] - v;
}

// ========== fill sorted (col, norm); rowstart finalized inline ==============
__global__ __launch_bounds__(256) void k_fill(const int* __restrict__ ei,
                                              const float* __restrict__ attr,
                                              const float* __restrict__ dinv,
                                              const int* __restrict__ rowstart,
                                              const int* __restrict__ partials,
                                              int* __restrict__ cnt,
                                              uint2* __restrict__ sorted) {
    int e = blockIdx.x * 256 + threadIdx.x;
    if (e >= N_EDGES) return;
    int r = ei[e];
    int c = ei[N_EDGES + e];
    float norm = dinv[r] * attr[e] * dinv[c];
    int base = rowstart[r] + partials[r >> 8];          // global exclusive scan
    int slot = atomicSub(&cnt[r], 1) - 1;
    sorted[base + slot] = make_uint2((unsigned)c, __float_as_uint(norm));
}

// ========== gather (fp16 in -> fp16 ag out): one wave per dest row ==========
__global__ __launch_bounds__(256) void k_gather_h(const int* __restrict__ rowstart,
                                                  const int* __restrict__ partials,
                                                  const uint2* __restrict__ sorted,
                                                  const _Float16* __restrict__ xi,
                                                  const float* __restrict__ dinv,
                                                  _Float16* __restrict__ ag,
                                                  float* __restrict__ s) {
    int r    = (int)(((size_t)blockIdx.x * 256 + threadIdx.x) >> 6);
    int lane = threadIdx.x & 63;
    if (r >= N_NODES) return;

    int start = rowstart[r] + partials[r >> 8];
    int end   = (r == N_NODES - 1) ? N_EDGES
                                   : rowstart[r + 1] + partials[(r + 1) >> 8];

    int idx = lane * 4;            // 0..252 over interleaved (b,f)

    float dn  = dinv[r];
    float nm0 = dn * dn;
    half4 hv  = *(const half4*)(xi + (size_t)r * BF + idx);
    float4 acc = make_float4(nm0 * (float)hv[0], nm0 * (float)hv[1],
                             nm0 * (float)hv[2], nm0 * (float)hv[3]);
    float snorm = nm0;

    for (int base = start; base < end; base += 64) {
        int m = end - base; if (m > 64) m = 64;
        uint2 en = make_uint2(0u, 0u);
        if (base + lane < end) en = sorted[base + lane];
        int   ec = (int)en.x;
        float ew = __uint_as_float(en.y);
        for (int j = 0; j < m; ++j) {
            int   c  = __shfl(ec, j);
            float nm = __shfl(ew, j);
            half4 v = *(const half4*)(xi + (size_t)c * BF + idx);
            acc.x += nm * (float)v[0]; acc.y += nm * (float)v[1];
            acc.z += nm * (float)v[2]; acc.w += nm * (float)v[3];
            snorm += nm;
        }
    }

    half4 ho;
    ho[0] = (_Float16)acc.x; ho[1] = (_Float16)acc.y;
    ho[2] = (_Float16)acc.z; ho[3] = (_Float16)acc.w;
    *(half4*)(ag + (size_t)r * BF + idx) = ho;
    if (lane == 0) s[r] = snorm;
}

// ========== gather fp32 fallback (writes fp32 out) ==========================
__global__ __launch_bounds__(256) void k_gather_f(const int* __restrict__ rowstart,
                                                  const int* __restrict__ partials,
                                                  const uint2* __restrict__ sorted,
                                                  const float* __restrict__ x,
                                                  const float* __restrict__ dinv,
                                                  float* __restrict__ out,
                                                  float* __restrict__ s) {
    int r    = (int)(((size_t)blockIdx.x * 256 + threadIdx.x) >> 6);
    int lane = threadIdx.x & 63;
    if (r >= N_NODES) return;

    int start = rowstart[r] + partials[r >> 8];
    int end   = (r == N_NODES - 1) ? N_EDGES
                                   : rowstart[r + 1] + partials[(r + 1) >> 8];

    int idx = lane * 4;
    int b = idx >> 7;
    int f = idx & 127;
    const float* xbf = x + (size_t)b * NF + f;

    float dn  = dinv[r];
    float nm0 = dn * dn;
    float4 v0 = *(const float4*)(xbf + (size_t)r * F);
    float4 acc = make_float4(nm0 * v0.x, nm0 * v0.y, nm0 * v0.z, nm0 * v0.w);
    float snorm = nm0;

    for (int base = start; base < end; base += 64) {
        int m = end - base; if (m > 64) m = 64;
        uint2 en = make_uint2(0u, 0u);
        if (base + lane < end) en = sorted[base + lane];
        int   ec = (int)en.x;
        float ew = __uint_as_float(en.y);
        for (int j = 0; j < m; ++j) {
            int   c  = __shfl(ec, j);
            float nm = __shfl(ew, j);
            const float4 v = *(const float4*)(xbf + (size_t)c * F);
            acc.x += nm * v.x; acc.y += nm * v.y;
            acc.z += nm * v.z; acc.w += nm * v.w;
            snorm += nm;
        }
    }

    *(float4*)(out + (size_t)b * NF + (size_t)r * F + f) = acc;
    if (lane == 0) s[r] = snorm;
}

// ========== atomic fallback pieces ==========================================
__global__ void k_deg(const int* __restrict__ ei, const float* __restrict__ attr,
                      float* __restrict__ deg) {
    int e = blockIdx.x * 256 + threadIdx.x;
    if (e < N_EDGES) atomicAdd(&deg[ei[e]], attr[e]);
}
__global__ void k_dinv(float* __restrict__ deg) {
    int n = blockIdx.x * 256 + threadIdx.x;
    if (n < N_NODES) deg[n] = rsqrtf(deg[n] + 1.0f);
}
__global__ __launch_bounds__(256) void k_edge(const int* __restrict__ ei,
                                              const float* __restrict__ attr,
                                              const float* __restrict__ dinv,
                                              const float* __restrict__ x,
                                              float* __restrict__ out,
                                              float* __restrict__ s) {
    int e    = (int)(((size_t)blockIdx.x * 256 + threadIdx.x) >> 6);
    int lane = threadIdx.x & 63;
    if (e >= N_EDGES) return;
    int r = ei[e];
    int c = ei[N_EDGES + e];
    float norm = dinv[r] * attr[e] * dinv[c];
    if (lane == 0) atomicAdd(&s[r], norm);
    int idx = lane * 4;
    int b = idx >> 7;
    int f = idx & 127;
    float4 v = *(const float4*)(x + (size_t)b * NF + (size_t)c * F + f);
    float* dst = out + (size_t)b * NF + (size_t)r * F + f;
    atomicAdd(dst + 0, norm * v.x);
    atomicAdd(dst + 1, norm * v.y);
    atomicAdd(dst + 2, norm * v.z);
    atomicAdd(dst + 3, norm * v.w);
}
__global__ void k_self(const float* __restrict__ x, const float* __restrict__ dinv,
                       float* __restrict__ out) {
    int i = blockIdx.x * 256 + threadIdx.x;
    if (i >= 2 * NF / 4) return;
    size_t base = (size_t)i * 4;
    int b = (base >= (size_t)NF) ? 1 : 0;
    size_t rem = base - (size_t)b * NF;
    int n = (int)(rem >> 7);
    float dn = dinv[n]; float sc = dn * dn;
    float4 v = *(const float4*)(x + base);
    float4* op = (float4*)(out + base);
    float4 o = *op;
    o.x += sc * v.x; o.y += sc * v.y; o.z += sc * v.z; o.w += sc * v.w;
    *op = o;
}
__global__ void k_sfix(const float* __restrict__ dinv, float* __restrict__ s) {
    int n = blockIdx.x * 256 + threadIdx.x;
    if (n < N_NODES) { float dn = dinv[n]; s[n] += dn * dn; }
}

// ========== MFMA GEMM, A direct from fp16 ag (T0 path) ======================
// out[b,n,:] = relu( ag[n, b*128 + :] @ fp16(W)^T + s[n]*bias )
__global__ __launch_bounds__(256) void k_gemm2(const _Float16* __restrict__ ag,
                                               const float* __restrict__ W,
                                               const float* __restrict__ bias,
                                               const float* __restrict__ s,
                                               float* __restrict__ out) {
    __shared__ _Float16 sW[128 * 136];
    const int tid = threadIdx.x;
    const int b   = blockIdx.y;
    const int n0  = blockIdx.x * 64;
    float* ob = out + (size_t)b * NF;

    // vectorized W staging: 16384 floats = 256 threads x 16 float4
    for (int i = 0; i < 16; ++i) {
        int idx = (i * 256 + tid) * 4;
        int o = idx >> 7, k = idx & 127;
        float4 w = *(const float4*)(W + idx);
        half4 h;
        h[0] = (_Float16)w.x; h[1] = (_Float16)w.y;
        h[2] = (_Float16)w.z; h[3] = (_Float16)w.w;
        *(half4*)&sW[o * 136 + k] = h;
    }
    __syncthreads();

    const int wave = tid >> 6, lane = tid & 63;
    const int ln = lane & 15, quad = lane >> 4;
    const int nw = wave * 16;
    if (n0 + nw >= N_NODES) return;        // N_NODES % 16 == 0

    const _Float16* arow = ag + (size_t)(n0 + nw + ln) * BF + b * F;

    floatx4 acc[8];
    for (int ot = 0; ot < 8; ++ot) acc[ot] = (floatx4){0.f, 0.f, 0.f, 0.f};

    for (int k0 = 0; k0 < 4; ++k0) {
        half8 a = *(const half8*)(arow + k0 * 32 + quad * 8);
        for (int ot = 0; ot < 8; ++ot) {
            half8 bf = *(const half8*)&sW[(ot * 16 + ln) * 136 + k0 * 32 + quad * 8];
            acc[ot] = __builtin_amdgcn_mfma_f32_16x16x32_f16(a, bf, acc[ot], 0, 0, 0);
        }
    }

    float sv[4];
    for (int rg = 0; rg < 4; ++rg) sv[rg] = s[n0 + nw + quad * 4 + rg];
    for (int ot = 0; ot < 8; ++ot) {
        int o = ot * 16 + ln;
        float bo = bias[o];
        for (int rg = 0; rg < 4; ++rg) {
            int n = n0 + nw + quad * 4 + rg;
            float v = acc[ot][rg] + sv[rg] * bo;
            ob[(size_t)n * F + o] = fmaxf(v, 0.0f);
        }
    }
}

// ========== MFMA GEMM, A from fp32 out via LDS (fallback paths) =============
__global__ __launch_bounds__(256) void k_gemm1(const float* __restrict__ W,
                                               const float* __restrict__ bias,
                                               const float* __restrict__ s,
                                               float* __restrict__ out) {
    __shared__ _Float16 sW[128 * 136];
    __shared__ _Float16 sA[64 * 136];
    const int tid = threadIdx.x;
    const int b   = blockIdx.y;
    const int n0  = blockIdx.x * 64;
    float* ob = out + (size_t)b * NF;

    for (int i = 0; i < 16; ++i) {
        int idx = (i * 256 + tid) * 4;
        int o = idx >> 7, k = idx & 127;
        float4 w = *(const float4*)(W + idx);
        half4 h;
        h[0] = (_Float16)w.x; h[1] = (_Float16)w.y;
        h[2] = (_Float16)w.z; h[3] = (_Float16)w.w;
        *(half4*)&sW[o * 136 + k] = h;
    }
    for (int i = 0; i < 8; ++i) {
        int idx = (i * 256 + tid) * 4;
        int nl = idx >> 7, k = idx & 127;
        int n = n0 + nl;
        half4 h = {(_Float16)0.f, (_Float16)0.f, (_Float16)0.f, (_Float16)0.f};
        if (n < N_NODES) {
            float4 v = *(const float4*)(ob + (size_t)n * F + k);
            h[0] = (_Float16)v.x; h[1] = (_Float16)v.y;
            h[2] = (_Float16)v.z; h[3] = (_Float16)v.w;
        }
        *(half4*)&sA[nl * 136 + k] = h;
    }
    __syncthreads();

    const int wave = tid >> 6, lane = tid & 63;
    const int ln = lane & 15, quad = lane >> 4;
    const int nw = wave * 16;
    if (n0 + nw >= N_NODES) return;

    floatx4 acc[8];
    for (int ot = 0; ot < 8; ++ot) acc[ot] = (floatx4){0.f, 0.f, 0.f, 0.f};

    for (int k0 = 0; k0 < 4; ++k0) {
        half8 a = *(const half8*)&sA[(nw + ln) * 136 + k0 * 32 + quad * 8];
        for (int ot = 0; ot < 8; ++ot) {
            half8 bf = *(const half8*)&sW[(ot * 16 + ln) * 136 + k0 * 32 + quad * 8];
            acc[ot] = __builtin_amdgcn_mfma_f32_16x16x32_f16(a, bf, acc[ot], 0, 0, 0);
        }
    }

    float sv[4];
    for (int rg = 0; rg < 4; ++rg) sv[rg] = s[n0 + nw + quad * 4 + rg];
    for (int ot = 0; ot < 8; ++ot) {
        int o = ot * 16 + ln;
        float bo = bias[o];
        for (int rg = 0; rg < 4; ++rg) {
            int n = n0 + nw + quad * 4 + rg;
            float v = acc[ot][rg] + sv[rg] * bo;
            ob[(size_t)n * F + o] = fmaxf(v, 0.0f);
        }
    }
}

extern "C" void kernel_launch(void* const* d_in, const int* in_sizes, int n_in,
                              void* d_out, int out_size, void* d_ws, size_t ws_size,
                              hipStream_t stream) {
    const float* x    = (const float*)d_in[0];
    const int*   ei   = (const int*)d_in[1];
    const float* attr = (const float*)d_in[2];
    const float* W    = (const float*)d_in[3];
    const float* bias = (const float*)d_in[4];
    float* out = (float*)d_out;

    // ws layout: deg[N] | cnt[N] | s[N] | rowstart[N] | partials[256] | pad16 |
    //            sorted[E]*8B | xi[2NF]*2B | ag[2NF]*2B
    float* deg      = (float*)d_ws;
    int*   cnt      = (int*)(deg + N_NODES);
    float* s        = (float*)(cnt + N_NODES);
    int*   rowstart = (int*)(s + N_NODES);
    int*   partials = rowstart + N_NODES;
    size_t sorted_off = ((size_t)((char*)(partials + 256) - (char*)d_ws) + 15) & ~(size_t)15;
    uint2* sorted   = (uint2*)((char*)d_ws + sorted_off);
    size_t xi_off   = sorted_off + (size_t)N_EDGES * 8;
    _Float16* xi    = (_Float16*)((char*)d_ws + xi_off);
    size_t ag_off   = xi_off + (size_t)2 * NF * 2;
    _Float16* ag    = (_Float16*)((char*)d_ws + ag_off);

    size_t need_T2 = xi_off;                       // CSR, fp32 gather
    size_t need_T1 = ag_off;                       // + xi fp16
    size_t need_T0 = ag_off + (size_t)2 * NF * 2;  // + ag fp16

    dim3 gg((N_NODES + 63) / 64, 2);

    if (ws_size >= need_T2) {
        hipMemsetAsync(deg, 0, 2 * N_NODES * sizeof(float), stream);  // deg + cnt

        int do_cvt = (ws_size >= need_T1) ? 1 : 0;
        k_pre<<<PRE_BLOCKS, 256, 0, stream>>>(ei, attr, x, deg, cnt, xi, do_cvt);
        k_scan1<<<SCAN_BLOCKS, 256, 0, stream>>>(deg, cnt, rowstart, partials);
        k_scan2<<<1, 256, 0, stream>>>(partials);
        k_fill<<<(N_EDGES + 255) / 256, 256, 0, stream>>>(ei, attr, deg, rowstart,
                                                          partials, cnt, sorted);

        size_t gthreads = (size_t)N_NODES * 64;
        unsigned gblocks = (unsigned)((gthreads + 255) / 256);
        if (ws_size >= need_T0) {
            k_gather_h<<<gblocks, 256, 0, stream>>>(rowstart, partials, sorted,
                                                    xi, deg, ag, s);
            k_gemm2<<<gg, 256, 0, stream>>>(ag, W, bias, s, out);
        } else if (ws_size >= need_T1) {
            // gather from fp16 xi but write fp32 out, then in-place gemm
            // (reuse fp32 gather on x to keep code simple & correct)
            k_gather_f<<<gblocks, 256, 0, stream>>>(rowstart, partials, sorted,
                                                    x, deg, out, s);
            k_gemm1<<<gg, 256, 0, stream>>>(W, bias, s, out);
        } else {
            k_gather_f<<<gblocks, 256, 0, stream>>>(rowstart, partials, sorted,
                                                    x, deg, out, s);
            k_gemm1<<<gg, 256, 0, stream>>>(W, bias, s, out);
        }
    } else {
        // atomic fallback: needs deg[N]+s[N] only
        hipMemsetAsync(deg, 0, N_NODES * sizeof(float), stream);
        hipMemsetAsync(s, 0, N_NODES * sizeof(float), stream);
        hipMemsetAsync(out, 0, (size_t)2 * NF * sizeof(float), stream);
        k_deg<<<(N_EDGES + 255) / 256, 256, 0, stream>>>(ei, attr, deg);
        k_dinv<<<(N_NODES + 255) / 256, 256, 0, stream>>>(deg);
        size_t edge_threads = (size_t)N_EDGES * 64;
        k_edge<<<(unsigned)((edge_threads + 255) / 256), 256, 0, stream>>>(
            ei, attr, deg, x, out, s);
        k_self<<<(2 * NF / 4 + 255) / 256, 256, 0, stream>>>(x, deg, out);
        k_sfix<<<(N_NODES + 255) / 256, 256, 0, stream>>>(deg, s);
        k_gemm1<<<gg, 256, 0, stream>>>(W, bias, s, out);
    }
}

// Round 6
// 280.347 us; speedup vs baseline: 10.5462x; 1.0859x over previous
//
#include <hip/hip_runtime.h>

#define N_NODES 50000
#define N_EDGES 800000
#define F 128
#define BF 256
#define NF (N_NODES * F)
#define SCAN_BLOCKS ((N_NODES + 255) / 256)   // 196
#define PRE_BLOCKS 3200
#define PRE_THREADS (PRE_BLOCKS * 256)        // 819200

typedef __attribute__((ext_vector_type(8))) _Float16 half8;
typedef __attribute__((ext_vector_type(4))) _Float16 half4;
typedef __attribute__((ext_vector_type(4))) float floatx4;

// ========== pre: edge count atomic (cnt only) + x -> fp16 interleaved =======
__global__ __launch_bounds__(256) void k_pre(const int* __restrict__ ei,
                                             int* __restrict__ cnt,
                                             const float* __restrict__ x,
                                             _Float16* __restrict__ xi,
                                             int do_cvt) {
    int t = blockIdx.x * 256 + threadIdx.x;
    if (t < N_EDGES) {
        atomicAdd(&cnt[ei[t]], 1);
    }
    if (do_cvt) {
        for (int i = t; i < 2 * NF / 4; i += PRE_THREADS) {
            size_t base = (size_t)i * 4;
            int b = (base >= (size_t)NF) ? 1 : 0;
            size_t rem = base - (size_t)b * NF;
            int n = (int)(rem >> 7);
            int f = (int)(rem & 127);
            float4 v = *(const float4*)(x + base);
            half4 h;
            h[0] = (_Float16)v.x; h[1] = (_Float16)v.y;
            h[2] = (_Float16)v.z; h[3] = (_Float16)v.w;
            *(half4*)(xi + (size_t)n * BF + b * F + f) = h;
        }
    }
}

// ========== scan1: per-block exclusive scan of cnt ==========================
__global__ __launch_bounds__(256) void k_scan1(const int* __restrict__ cnt,
                                               int* __restrict__ rowstart,
                                               int* __restrict__ partials) {
    __shared__ int tmp[256];
    int i = blockIdx.x * 256 + threadIdx.x;
    int v = (i < N_NODES) ? cnt[i] : 0;
    tmp[threadIdx.x] = v;
    __syncthreads();
    for (int off = 1; off < 256; off <<= 1) {
        int t = (threadIdx.x >= off) ? tmp[threadIdx.x - off] : 0;
        __syncthreads();
        tmp[threadIdx.x] += t;
        __syncthreads();
    }
    if (i < N_NODES) rowstart[i] = tmp[threadIdx.x] - v;   // block-local exclusive
    if (threadIdx.x == 255) partials[blockIdx.x] = tmp[255];
}

__global__ __launch_bounds__(256) void k_scan2(int* __restrict__ partials) {
    __shared__ int tmp[256];
    int v = (threadIdx.x < SCAN_BLOCKS) ? partials[threadIdx.x] : 0;
    tmp[threadIdx.x] = v;
    __syncthreads();
    for (int off = 1; off < 256; off <<= 1) {
        int t = (threadIdx.x >= off) ? tmp[threadIdx.x - off] : 0;
        __syncthreads();
        tmp[threadIdx.x] += t;
        __syncthreads();
    }
    if (threadIdx.x < SCAN_BLOCKS) partials[threadIdx.x] = tmp[threadIdx.x] - v;
}

// ========== fill sorted (col, attr) per dest row ============================
__global__ __launch_bounds__(256) void k_fill(const int* __restrict__ ei,
                                              const float* __restrict__ attr,
                                              const int* __restrict__ rowstart,
                                              const int* __restrict__ partials,
                                              int* __restrict__ cnt,
                                              uint2* __restrict__ sorted) {
    int e = blockIdx.x * 256 + threadIdx.x;
    if (e >= N_EDGES) return;
    int r = ei[e];
    int c = ei[N_EDGES + e];
    int base = rowstart[r] + partials[r >> 8];          // global exclusive scan
    int slot = atomicSub(&cnt[r], 1) - 1;
    sorted[base + slot] = make_uint2((unsigned)c, __float_as_uint(attr[e]));
}

// ========== deg via segmented sum (no atomics): dinv[r]=rsqrt(1+sum attr) ===
__global__ __launch_bounds__(256) void k_deg_seg(const int* __restrict__ rowstart,
                                                 const int* __restrict__ partials,
                                                 const uint2* __restrict__ sorted,
                                                 float* __restrict__ dinv) {
    int r    = (int)(((size_t)blockIdx.x * 256 + threadIdx.x) >> 6);
    int lane = threadIdx.x & 63;
    if (r >= N_NODES) return;
    int start = rowstart[r] + partials[r >> 8];
    int end   = (r == N_NODES - 1) ? N_EDGES
                                   : rowstart[r + 1] + partials[(r + 1) >> 8];
    float sum = 0.0f;
    for (int base = start; base < end; base += 64) {
        if (base + lane < end) sum += __uint_as_float(sorted[base + lane].y);
    }
    for (int off = 32; off > 0; off >>= 1) sum += __shfl_down(sum, off);
    if (lane == 0) dinv[r] = rsqrtf(sum + 1.0f);
}

// ========== gather (fp16 in -> fp16 ag out), norm computed inline ===========
__global__ __launch_bounds__(256) void k_gather_h(const int* __restrict__ rowstart,
                                                  const int* __restrict__ partials,
                                                  const uint2* __restrict__ sorted,
                                                  const _Float16* __restrict__ xi,
                                                  const float* __restrict__ dinv,
                                                  _Float16* __restrict__ ag,
                                                  float* __restrict__ s) {
    int r    = (int)(((size_t)blockIdx.x * 256 + threadIdx.x) >> 6);
    int lane = threadIdx.x & 63;
    if (r >= N_NODES) return;

    int start = rowstart[r] + partials[r >> 8];
    int end   = (r == N_NODES - 1) ? N_EDGES
                                   : rowstart[r + 1] + partials[(r + 1) >> 8];

    int idx = lane * 4;            // 0..252 over interleaved (b,f)

    float dinvr = dinv[r];
    float nm0   = dinvr * dinvr;
    half4 hv    = *(const half4*)(xi + (size_t)r * BF + idx);
    float4 acc = make_float4(nm0 * (float)hv[0], nm0 * (float)hv[1],
                             nm0 * (float)hv[2], nm0 * (float)hv[3]);
    float snorm = nm0;

    for (int base = start; base < end; base += 64) {
        int m = end - base; if (m > 64) m = 64;
        int   ec = 0;
        float pw = 0.0f;           // attr * dinv[c], this lane's entry
        if (base + lane < end) {
            uint2 en = sorted[base + lane];
            ec = (int)en.x;
            pw = __uint_as_float(en.y) * dinv[ec];
        }
        for (int j = 0; j < m; ++j) {
            int   c  = __shfl(ec, j);
            float nm = dinvr * __shfl(pw, j);
            half4 v = *(const half4*)(xi + (size_t)c * BF + idx);
            acc.x += nm * (float)v[0]; acc.y += nm * (float)v[1];
            acc.z += nm * (float)v[2]; acc.w += nm * (float)v[3];
            snorm += nm;
        }
    }

    half4 ho;
    ho[0] = (_Float16)acc.x; ho[1] = (_Float16)acc.y;
    ho[2] = (_Float16)acc.z; ho[3] = (_Float16)acc.w;
    *(half4*)(ag + (size_t)r * BF + idx) = ho;
    if (lane == 0) s[r] = snorm;
}

// ========== gather fp32 fallback (writes fp32 out), norm inline =============
__global__ __launch_bounds__(256) void k_gather_f(const int* __restrict__ rowstart,
                                                  const int* __restrict__ partials,
                                                  const uint2* __restrict__ sorted,
                                                  const float* __restrict__ x,
                                                  const float* __restrict__ dinv,
                                                  float* __restrict__ out,
                                                  float* __restrict__ s) {
    int r    = (int)(((size_t)blockIdx.x * 256 + threadIdx.x) >> 6);
    int lane = threadIdx.x & 63;
    if (r >= N_NODES) return;

    int start = rowstart[r] + partials[r >> 8];
    int end   = (r == N_NODES - 1) ? N_EDGES
                                   : rowstart[r + 1] + partials[(r + 1) >> 8];

    int idx = lane * 4;
    int b = idx >> 7;
    int f = idx & 127;
    const float* xbf = x + (size_t)b * NF + f;

    float dinvr = dinv[r];
    float nm0   = dinvr * dinvr;
    float4 v0 = *(const float4*)(xbf + (size_t)r * F);
    float4 acc = make_float4(nm0 * v0.x, nm0 * v0.y, nm0 * v0.z, nm0 * v0.w);
    float snorm = nm0;

    for (int base = start; base < end; base += 64) {
        int m = end - base; if (m > 64) m = 64;
        int   ec = 0;
        float pw = 0.0f;
        if (base + lane < end) {
            uint2 en = sorted[base + lane];
            ec = (int)en.x;
            pw = __uint_as_float(en.y) * dinv[ec];
        }
        for (int j = 0; j < m; ++j) {
            int   c  = __shfl(ec, j);
            float nm = dinvr * __shfl(pw, j);
            const float4 v = *(const float4*)(xbf + (size_t)c * F);
            acc.x += nm * v.x; acc.y += nm * v.y;
            acc.z += nm * v.z; acc.w += nm * v.w;
            snorm += nm;
        }
    }

    *(float4*)(out + (size_t)b * NF + (size_t)r * F + f) = acc;
    if (lane == 0) s[r] = snorm;
}

// ========== atomic fallback pieces (tiny ws) ================================
__global__ void k_deg(const int* __restrict__ ei, const float* __restrict__ attr,
                      float* __restrict__ deg) {
    int e = blockIdx.x * 256 + threadIdx.x;
    if (e < N_EDGES) atomicAdd(&deg[ei[e]], attr[e]);
}
__global__ void k_dinv(float* __restrict__ deg) {
    int n = blockIdx.x * 256 + threadIdx.x;
    if (n < N_NODES) deg[n] = rsqrtf(deg[n] + 1.0f);
}
__global__ __launch_bounds__(256) void k_edge(const int* __restrict__ ei,
                                              const float* __restrict__ attr,
                                              const float* __restrict__ dinv,
                                              const float* __restrict__ x,
                                              float* __restrict__ out,
                                              float* __restrict__ s) {
    int e    = (int)(((size_t)blockIdx.x * 256 + threadIdx.x) >> 6);
    int lane = threadIdx.x & 63;
    if (e >= N_EDGES) return;
    int r = ei[e];
    int c = ei[N_EDGES + e];
    float norm = dinv[r] * attr[e] * dinv[c];
    if (lane == 0) atomicAdd(&s[r], norm);
    int idx = lane * 4;
    int b = idx >> 7;
    int f = idx & 127;
    float4 v = *(const float4*)(x + (size_t)b * NF + (size_t)c * F + f);
    float* dst = out + (size_t)b * NF + (size_t)r * F + f;
    atomicAdd(dst + 0, norm * v.x);
    atomicAdd(dst + 1, norm * v.y);
    atomicAdd(dst + 2, norm * v.z);
    atomicAdd(dst + 3, norm * v.w);
}
__global__ void k_self(const float* __restrict__ x, const float* __restrict__ dinv,
                       float* __restrict__ out) {
    int i = blockIdx.x * 256 + threadIdx.x;
    if (i >= 2 * NF / 4) return;
    size_t base = (size_t)i * 4;
    int b = (base >= (size_t)NF) ? 1 : 0;
    size_t rem = base - (size_t)b * NF;
    int n = (int)(rem >> 7);
    float dn = dinv[n]; float sc = dn * dn;
    float4 v = *(const float4*)(x + base);
    float4* op = (float4*)(out + base);
    float4 o = *op;
    o.x += sc * v.x; o.y += sc * v.y; o.z += sc * v.z; o.w += sc * v.w;
    *op = o;
}
__global__ void k_sfix(const float* __restrict__ dinv, float* __restrict__ s) {
    int n = blockIdx.x * 256 + threadIdx.x;
    if (n < N_NODES) { float dn = dinv[n]; s[n] += dn * dn; }
}

// ========== MFMA GEMM, A direct from fp16 ag (T0 path) ======================
__global__ __launch_bounds__(256) void k_gemm2(const _Float16* __restrict__ ag,
                                               const float* __restrict__ W,
                                               const float* __restrict__ bias,
                                               const float* __restrict__ s,
                                               float* __restrict__ out) {
    __shared__ _Float16 sW[128 * 136];
    const int tid = threadIdx.x;
    const int b   = blockIdx.y;
    const int n0  = blockIdx.x * 64;
    float* ob = out + (size_t)b * NF;

    for (int i = 0; i < 16; ++i) {
        int idx = (i * 256 + tid) * 4;
        int o = idx >> 7, k = idx & 127;
        float4 w = *(const float4*)(W + idx);
        half4 h;
        h[0] = (_Float16)w.x; h[1] = (_Float16)w.y;
        h[2] = (_Float16)w.z; h[3] = (_Float16)w.w;
        *(half4*)&sW[o * 136 + k] = h;
    }
    __syncthreads();

    const int wave = tid >> 6, lane = tid & 63;
    const int ln = lane & 15, quad = lane >> 4;
    const int nw = wave * 16;
    if (n0 + nw >= N_NODES) return;        // N_NODES % 16 == 0

    const _Float16* arow = ag + (size_t)(n0 + nw + ln) * BF + b * F;

    floatx4 acc[8];
    for (int ot = 0; ot < 8; ++ot) acc[ot] = (floatx4){0.f, 0.f, 0.f, 0.f};

    for (int k0 = 0; k0 < 4; ++k0) {
        half8 a = *(const half8*)(arow + k0 * 32 + quad * 8);
        for (int ot = 0; ot < 8; ++ot) {
            half8 bf = *(const half8*)&sW[(ot * 16 + ln) * 136 + k0 * 32 + quad * 8];
            acc[ot] = __builtin_amdgcn_mfma_f32_16x16x32_f16(a, bf, acc[ot], 0, 0, 0);
        }
    }

    float sv[4];
    for (int rg = 0; rg < 4; ++rg) sv[rg] = s[n0 + nw + quad * 4 + rg];
    for (int ot = 0; ot < 8; ++ot) {
        int o = ot * 16 + ln;
        float bo = bias[o];
        for (int rg = 0; rg < 4; ++rg) {
            int n = n0 + nw + quad * 4 + rg;
            float v = acc[ot][rg] + sv[rg] * bo;
            ob[(size_t)n * F + o] = fmaxf(v, 0.0f);
        }
    }
}

// ========== MFMA GEMM, A from fp32 out via LDS (fallback paths) =============
__global__ __launch_bounds__(256) void k_gemm1(const float* __restrict__ W,
                                               const float* __restrict__ bias,
                                               const float* __restrict__ s,
                                               float* __restrict__ out) {
    __shared__ _Float16 sW[128 * 136];
    __shared__ _Float16 sA[64 * 136];
    const int tid = threadIdx.x;
    const int b   = blockIdx.y;
    const int n0  = blockIdx.x * 64;
    float* ob = out + (size_t)b * NF;

    for (int i = 0; i < 16; ++i) {
        int idx = (i * 256 + tid) * 4;
        int o = idx >> 7, k = idx & 127;
        float4 w = *(const float4*)(W + idx);
        half4 h;
        h[0] = (_Float16)w.x; h[1] = (_Float16)w.y;
        h[2] = (_Float16)w.z; h[3] = (_Float16)w.w;
        *(half4*)&sW[o * 136 + k] = h;
    }
    for (int i = 0; i < 8; ++i) {
        int idx = (i * 256 + tid) * 4;
        int nl = idx >> 7, k = idx & 127;
        int n = n0 + nl;
        half4 h = {(_Float16)0.f, (_Float16)0.f, (_Float16)0.f, (_Float16)0.f};
        if (n < N_NODES) {
            float4 v = *(const float4*)(ob + (size_t)n * F + k);
            h[0] = (_Float16)v.x; h[1] = (_Float16)v.y;
            h[2] = (_Float16)v.z; h[3] = (_Float16)v.w;
        }
        *(half4*)&sA[nl * 136 + k] = h;
    }
    __syncthreads();

    const int wave = tid >> 6, lane = tid & 63;
    const int ln = lane & 15, quad = lane >> 4;
    const int nw = wave * 16;
    if (n0 + nw >= N_NODES) return;

    floatx4 acc[8];
    for (int ot = 0; ot < 8; ++ot) acc[ot] = (floatx4){0.f, 0.f, 0.f, 0.f};

    for (int k0 = 0; k0 < 4; ++k0) {
        half8 a = *(const half8*)&sA[(nw + ln) * 136 + k0 * 32 + quad * 8];
        for (int ot = 0; ot < 8; ++ot) {
            half8 bf = *(const half8*)&sW[(ot * 16 + ln) * 136 + k0 * 32 + quad * 8];
            acc[ot] = __builtin_amdgcn_mfma_f32_16x16x32_f16(a, bf, acc[ot], 0, 0, 0);
        }
    }

    float sv[4];
    for (int rg = 0; rg < 4; ++rg) sv[rg] = s[n0 + nw + quad * 4 + rg];
    for (int ot = 0; ot < 8; ++ot) {
        int o = ot * 16 + ln;
        float bo = bias[o];
        for (int rg = 0; rg < 4; ++rg) {
            int n = n0 + nw + quad * 4 + rg;
            float v = acc[ot][rg] + sv[rg] * bo;
            ob[(size_t)n * F + o] = fmaxf(v, 0.0f);
        }
    }
}

extern "C" void kernel_launch(void* const* d_in, const int* in_sizes, int n_in,
                              void* d_out, int out_size, void* d_ws, size_t ws_size,
                              hipStream_t stream) {
    const float* x    = (const float*)d_in[0];
    const int*   ei   = (const int*)d_in[1];
    const float* attr = (const float*)d_in[2];
    const float* W    = (const float*)d_in[3];
    const float* bias = (const float*)d_in[4];
    float* out = (float*)d_out;

    // ws layout: cnt[N] | dinv[N] | s[N] | rowstart[N] | partials[256] | pad16 |
    //            sorted[E]*8B | xi[2NF]*2B | ag[2NF]*2B
    int*   cnt      = (int*)d_ws;
    float* dinv     = (float*)(cnt + N_NODES);
    float* s        = dinv + N_NODES;
    int*   rowstart = (int*)(s + N_NODES);
    int*   partials = rowstart + N_NODES;
    size_t sorted_off = ((size_t)((char*)(partials + 256) - (char*)d_ws) + 15) & ~(size_t)15;
    uint2* sorted   = (uint2*)((char*)d_ws + sorted_off);
    size_t xi_off   = sorted_off + (size_t)N_EDGES * 8;
    _Float16* xi    = (_Float16*)((char*)d_ws + xi_off);
    size_t ag_off   = xi_off + (size_t)2 * NF * 2;
    _Float16* ag    = (_Float16*)((char*)d_ws + ag_off);

    size_t need_T2 = xi_off;                       // CSR, fp32 gather
    size_t need_T0 = ag_off + (size_t)2 * NF * 2;  // + xi + ag fp16

    dim3 gg((N_NODES + 63) / 64, 2);
    size_t rthreads = (size_t)N_NODES * 64;
    unsigned rblocks = (unsigned)((rthreads + 255) / 256);

    if (ws_size >= need_T2) {
        hipMemsetAsync(cnt, 0, N_NODES * sizeof(int), stream);

        int do_cvt = (ws_size >= need_T0) ? 1 : 0;
        k_pre<<<PRE_BLOCKS, 256, 0, stream>>>(ei, cnt, x, xi, do_cvt);
        k_scan1<<<SCAN_BLOCKS, 256, 0, stream>>>(cnt, rowstart, partials);
        k_scan2<<<1, 256, 0, stream>>>(partials);
        k_fill<<<(N_EDGES + 255) / 256, 256, 0, stream>>>(ei, attr, rowstart,
                                                          partials, cnt, sorted);
        k_deg_seg<<<rblocks, 256, 0, stream>>>(rowstart, partials, sorted, dinv);

        if (ws_size >= need_T0) {
            k_gather_h<<<rblocks, 256, 0, stream>>>(rowstart, partials, sorted,
                                                    xi, dinv, ag, s);
            k_gemm2<<<gg, 256, 0, stream>>>(ag, W, bias, s, out);
        } else {
            k_gather_f<<<rblocks, 256, 0, stream>>>(rowstart, partials, sorted,
                                                    x, dinv, out, s);
            k_gemm1<<<gg, 256, 0, stream>>>(W, bias, s, out);
        }
    } else {
        // atomic fallback: needs dinv[N]+s[N] only
        hipMemsetAsync(dinv, 0, N_NODES * sizeof(float), stream);
        hipMemsetAsync(s, 0, N_NODES * sizeof(float), stream);
        hipMemsetAsync(out, 0, (size_t)2 * NF * sizeof(float), stream);
        k_deg<<<(N_EDGES + 255) / 256, 256, 0, stream>>>(ei, attr, dinv);
        k_dinv<<<(N_NODES + 255) / 256, 256, 0, stream>>>(dinv);
        size_t edge_threads = (size_t)N_EDGES * 64;
        k_edge<<<(unsigned)((edge_threads + 255) / 256), 256, 0, stream>>>(
            ei, attr, dinv, x, out, s);
        k_self<<<(2 * NF / 4 + 255) / 256, 256, 0, stream>>>(x, dinv, out);
        k_sfix<<<(N_NODES + 255) / 256, 256, 0, stream>>>(dinv, s);
        k_gemm1<<<gg, 256, 0, stream>>>(W, bias, s, out);
    }
}

// Round 7
// 273.800 us; speedup vs baseline: 10.7984x; 1.0239x over previous
//
#include <hip/hip_runtime.h>

#define N_NODES 50000
#define N_EDGES 800000
#define F 128
#define BF 256
#define NF (N_NODES * F)
#define SCAN_BLOCKS ((N_NODES + 255) / 256)   // 196
#define PRE_BLOCKS 3200
#define PRE_THREADS (PRE_BLOCKS * 256)        // 819200

typedef __attribute__((ext_vector_type(8))) _Float16 half8;
typedef __attribute__((ext_vector_type(4))) _Float16 half4;
typedef __attribute__((ext_vector_type(4))) float floatx4;

// ========== pre: sharded edge count atomic + x -> fp16 interleaved ==========
// replica = (edge >> 8) & 3  (i.e. blockIdx & 3) — 4x less same-address contention
__global__ __launch_bounds__(256) void k_pre(const int* __restrict__ ei,
                                             int* __restrict__ cnt,      // [4][N]
                                             const float* __restrict__ x,
                                             _Float16* __restrict__ xi,
                                             int do_cvt) {
    int t = blockIdx.x * 256 + threadIdx.x;
    if (t < N_EDGES) {
        int ri = (t >> 8) & 3;
        atomicAdd(&cnt[ri * N_NODES + ei[t]], 1);
    }
    if (do_cvt) {
        for (int i = t; i < 2 * NF / 4; i += PRE_THREADS) {
            size_t base = (size_t)i * 4;
            int b = (base >= (size_t)NF) ? 1 : 0;
            size_t rem = base - (size_t)b * NF;
            int n = (int)(rem >> 7);
            int f = (int)(rem & 127);
            float4 v = *(const float4*)(x + base);
            half4 h;
            h[0] = (_Float16)v.x; h[1] = (_Float16)v.y;
            h[2] = (_Float16)v.z; h[3] = (_Float16)v.w;
            *(half4*)(xi + (size_t)n * BF + b * F + f) = h;
        }
    }
}

// ========== scan1: block-exclusive scan of per-node totals + replica offsets
__global__ __launch_bounds__(256) void k_scan1(const int* __restrict__ cnt,   // [4][N]
                                               int* __restrict__ rowstart,
                                               int* __restrict__ rofs,        // [4][N]
                                               int* __restrict__ partials) {
    __shared__ int tmp[256];
    int i = blockIdx.x * 256 + threadIdx.x;
    int c0 = 0, c1 = 0, c2 = 0, c3 = 0;
    if (i < N_NODES) {
        c0 = cnt[i];
        c1 = cnt[N_NODES + i];
        c2 = cnt[2 * N_NODES + i];
        c3 = cnt[3 * N_NODES + i];
    }
    int tot = c0 + c1 + c2 + c3;
    tmp[threadIdx.x] = tot;
    __syncthreads();
    for (int off = 1; off < 256; off <<= 1) {
        int t = (threadIdx.x >= off) ? tmp[threadIdx.x - off] : 0;
        __syncthreads();
        tmp[threadIdx.x] += t;
        __syncthreads();
    }
    int ex = tmp[threadIdx.x] - tot;   // block-local exclusive
    if (i < N_NODES) {
        rowstart[i] = ex;
        rofs[i]                 = ex;
        rofs[N_NODES + i]       = ex + c0;
        rofs[2 * N_NODES + i]   = ex + c0 + c1;
        rofs[3 * N_NODES + i]   = ex + c0 + c1 + c2;
    }
    if (threadIdx.x == 255) partials[blockIdx.x] = tmp[255];
}

__global__ __launch_bounds__(256) void k_scan2(int* __restrict__ partials) {
    __shared__ int tmp[256];
    int v = (threadIdx.x < SCAN_BLOCKS) ? partials[threadIdx.x] : 0;
    tmp[threadIdx.x] = v;
    __syncthreads();
    for (int off = 1; off < 256; off <<= 1) {
        int t = (threadIdx.x >= off) ? tmp[threadIdx.x - off] : 0;
        __syncthreads();
        tmp[threadIdx.x] += t;
        __syncthreads();
    }
    if (threadIdx.x < SCAN_BLOCKS) partials[threadIdx.x] = tmp[threadIdx.x] - v;
}

// ========== fill sorted (col, attr) per dest row, sharded counters ==========
__global__ __launch_bounds__(256) void k_fill(const int* __restrict__ ei,
                                              const float* __restrict__ attr,
                                              const int* __restrict__ rofs,   // [4][N]
                                              const int* __restrict__ partials,
                                              int* __restrict__ cnt,          // [4][N]
                                              uint2* __restrict__ sorted) {
    int e = blockIdx.x * 256 + threadIdx.x;
    if (e >= N_EDGES) return;
    int r = ei[e];
    int c = ei[N_EDGES + e];
    int ri = (e >> 8) & 3;                      // must match k_pre's mapping
    int base = rofs[ri * N_NODES + r] + partials[r >> 8];
    int slot = atomicSub(&cnt[ri * N_NODES + r], 1) - 1;
    sorted[base + slot] = make_uint2((unsigned)c, __float_as_uint(attr[e]));
}

// ========== deg via segmented sum: dinv[r]=rsqrt(1+sum attr) ================
__global__ __launch_bounds__(256) void k_deg_seg(const int* __restrict__ rowstart,
                                                 const int* __restrict__ partials,
                                                 const uint2* __restrict__ sorted,
                                                 float* __restrict__ dinv) {
    int r    = (int)(((size_t)blockIdx.x * 256 + threadIdx.x) >> 6);
    int lane = threadIdx.x & 63;
    if (r >= N_NODES) return;
    int start = rowstart[r] + partials[r >> 8];
    int end   = (r == N_NODES - 1) ? N_EDGES
                                   : rowstart[r + 1] + partials[(r + 1) >> 8];
    float sum = 0.0f;
    for (int base = start; base < end; base += 64) {
        if (base + lane < end) sum += __uint_as_float(sorted[base + lane].y);
    }
    for (int off = 32; off > 0; off >>= 1) sum += __shfl_down(sum, off);
    if (lane == 0) dinv[r] = rsqrtf(sum + 1.0f);
}

// ========== gather (fp16 in -> fp16 ag out), 4x unrolled for ILP ============
__global__ __launch_bounds__(256) void k_gather_h(const int* __restrict__ rowstart,
                                                  const int* __restrict__ partials,
                                                  const uint2* __restrict__ sorted,
                                                  const _Float16* __restrict__ xi,
                                                  const float* __restrict__ dinv,
                                                  _Float16* __restrict__ ag,
                                                  float* __restrict__ s) {
    int r    = (int)(((size_t)blockIdx.x * 256 + threadIdx.x) >> 6);
    int lane = threadIdx.x & 63;
    if (r >= N_NODES) return;

    int start = rowstart[r] + partials[r >> 8];
    int end   = (r == N_NODES - 1) ? N_EDGES
                                   : rowstart[r + 1] + partials[(r + 1) >> 8];

    int idx = lane * 4;            // 0..252 over interleaved (b,f)

    float dinvr = dinv[r];
    float nm0   = dinvr * dinvr;
    half4 hv    = *(const half4*)(xi + (size_t)r * BF + idx);   // self row

    float4 acc = make_float4(0.f, 0.f, 0.f, 0.f);   // edge part: sum pw * x[c]
    float sp = 0.0f;                                // sum pw = sum attr*dinv[c]

    for (int base = start; base < end; base += 64) {
        int m = end - base; if (m > 64) m = 64;
        int   ec = 0;
        float pw = 0.0f;
        if (base + lane < end) {
            uint2 en = sorted[base + lane];
            ec = (int)en.x;
            pw = __uint_as_float(en.y) * dinv[ec];
        }
        int j = 0;
        for (; j + 4 <= m; j += 4) {
            int   c0 = __shfl(ec, j),     c1 = __shfl(ec, j + 1);
            int   c2 = __shfl(ec, j + 2), c3 = __shfl(ec, j + 3);
            float p0 = __shfl(pw, j),     p1 = __shfl(pw, j + 1);
            float p2 = __shfl(pw, j + 2), p3 = __shfl(pw, j + 3);
            half4 v0 = *(const half4*)(xi + (size_t)c0 * BF + idx);
            half4 v1 = *(const half4*)(xi + (size_t)c1 * BF + idx);
            half4 v2 = *(const half4*)(xi + (size_t)c2 * BF + idx);
            half4 v3 = *(const half4*)(xi + (size_t)c3 * BF + idx);
            acc.x += p0 * (float)v0[0] + p1 * (float)v1[0]
                   + p2 * (float)v2[0] + p3 * (float)v3[0];
            acc.y += p0 * (float)v0[1] + p1 * (float)v1[1]
                   + p2 * (float)v2[1] + p3 * (float)v3[1];
            acc.z += p0 * (float)v0[2] + p1 * (float)v1[2]
                   + p2 * (float)v2[2] + p3 * (float)v3[2];
            acc.w += p0 * (float)v0[3] + p1 * (float)v1[3]
                   + p2 * (float)v2[3] + p3 * (float)v3[3];
            sp += p0 + p1 + p2 + p3;
        }
        for (; j < m; ++j) {
            int   c = __shfl(ec, j);
            float p = __shfl(pw, j);
            half4 v = *(const half4*)(xi + (size_t)c * BF + idx);
            acc.x += p * (float)v[0]; acc.y += p * (float)v[1];
            acc.z += p * (float)v[2]; acc.w += p * (float)v[3];
            sp += p;
        }
    }

    half4 ho;
    ho[0] = (_Float16)(dinvr * acc.x + nm0 * (float)hv[0]);
    ho[1] = (_Float16)(dinvr * acc.y + nm0 * (float)hv[1]);
    ho[2] = (_Float16)(dinvr * acc.z + nm0 * (float)hv[2]);
    ho[3] = (_Float16)(dinvr * acc.w + nm0 * (float)hv[3]);
    *(half4*)(ag + (size_t)r * BF + idx) = ho;
    if (lane == 0) s[r] = dinvr * sp + nm0;
}

// ========== gather fp32 fallback (writes fp32 out) ==========================
__global__ __launch_bounds__(256) void k_gather_f(const int* __restrict__ rowstart,
                                                  const int* __restrict__ partials,
                                                  const uint2* __restrict__ sorted,
                                                  const float* __restrict__ x,
                                                  const float* __restrict__ dinv,
                                                  float* __restrict__ out,
                                                  float* __restrict__ s) {
    int r    = (int)(((size_t)blockIdx.x * 256 + threadIdx.x) >> 6);
    int lane = threadIdx.x & 63;
    if (r >= N_NODES) return;

    int start = rowstart[r] + partials[r >> 8];
    int end   = (r == N_NODES - 1) ? N_EDGES
                                   : rowstart[r + 1] + partials[(r + 1) >> 8];

    int idx = lane * 4;
    int b = idx >> 7;
    int f = idx & 127;
    const float* xbf = x + (size_t)b * NF + f;

    float dinvr = dinv[r];
    float nm0   = dinvr * dinvr;
    float4 v0s = *(const float4*)(xbf + (size_t)r * F);
    float4 acc = make_float4(0.f, 0.f, 0.f, 0.f);
    float sp = 0.0f;

    for (int base = start; base < end; base += 64) {
        int m = end - base; if (m > 64) m = 64;
        int   ec = 0;
        float pw = 0.0f;
        if (base + lane < end) {
            uint2 en = sorted[base + lane];
            ec = (int)en.x;
            pw = __uint_as_float(en.y) * dinv[ec];
        }
        for (int j = 0; j < m; ++j) {
            int   c = __shfl(ec, j);
            float p = __shfl(pw, j);
            const float4 v = *(const float4*)(xbf + (size_t)c * F);
            acc.x += p * v.x; acc.y += p * v.y;
            acc.z += p * v.z; acc.w += p * v.w;
            sp += p;
        }
    }

    float4 res = make_float4(dinvr * acc.x + nm0 * v0s.x,
                             dinvr * acc.y + nm0 * v0s.y,
                             dinvr * acc.z + nm0 * v0s.z,
                             dinvr * acc.w + nm0 * v0s.w);
    *(float4*)(out + (size_t)b * NF + (size_t)r * F + f) = res;
    if (lane == 0) s[r] = dinvr * sp + nm0;
}

// ========== atomic fallback pieces (tiny ws) ================================
__global__ void k_deg(const int* __restrict__ ei, const float* __restrict__ attr,
                      float* __restrict__ deg) {
    int e = blockIdx.x * 256 + threadIdx.x;
    if (e < N_EDGES) atomicAdd(&deg[ei[e]], attr[e]);
}
__global__ void k_dinv(float* __restrict__ deg) {
    int n = blockIdx.x * 256 + threadIdx.x;
    if (n < N_NODES) deg[n] = rsqrtf(deg[n] + 1.0f);
}
__global__ __launch_bounds__(256) void k_edge(const int* __restrict__ ei,
                                              const float* __restrict__ attr,
                                              const float* __restrict__ dinv,
                                              const float* __restrict__ x,
                                              float* __restrict__ out,
                                              float* __restrict__ s) {
    int e    = (int)(((size_t)blockIdx.x * 256 + threadIdx.x) >> 6);
    int lane = threadIdx.x & 63;
    if (e >= N_EDGES) return;
    int r = ei[e];
    int c = ei[N_EDGES + e];
    float norm = dinv[r] * attr[e] * dinv[c];
    if (lane == 0) atomicAdd(&s[r], norm);
    int idx = lane * 4;
    int b = idx >> 7;
    int f = idx & 127;
    float4 v = *(const float4*)(x + (size_t)b * NF + (size_t)c * F + f);
    float* dst = out + (size_t)b * NF + (size_t)r * F + f;
    atomicAdd(dst + 0, norm * v.x);
    atomicAdd(dst + 1, norm * v.y);
    atomicAdd(dst + 2, norm * v.z);
    atomicAdd(dst + 3, norm * v.w);
}
__global__ void k_self(const float* __restrict__ x, const float* __restrict__ dinv,
                       float* __restrict__ out) {
    int i = blockIdx.x * 256 + threadIdx.x;
    if (i >= 2 * NF / 4) return;
    size_t base = (size_t)i * 4;
    int b = (base >= (size_t)NF) ? 1 : 0;
    size_t rem = base - (size_t)b * NF;
    int n = (int)(rem >> 7);
    float dn = dinv[n]; float sc = dn * dn;
    float4 v = *(const float4*)(x + base);
    float4* op = (float4*)(out + base);
    float4 o = *op;
    o.x += sc * v.x; o.y += sc * v.y; o.z += sc * v.z; o.w += sc * v.w;
    *op = o;
}
__global__ void k_sfix(const float* __restrict__ dinv, float* __restrict__ s) {
    int n = blockIdx.x * 256 + threadIdx.x;
    if (n < N_NODES) { float dn = dinv[n]; s[n] += dn * dn; }
}

// ========== MFMA GEMM, A direct from fp16 ag (T0 path) ======================
__global__ __launch_bounds__(256) void k_gemm2(const _Float16* __restrict__ ag,
                                               const float* __restrict__ W,
                                               const float* __restrict__ bias,
                                               const float* __restrict__ s,
                                               float* __restrict__ out) {
    __shared__ _Float16 sW[128 * 136];
    const int tid = threadIdx.x;
    const int b   = blockIdx.y;
    const int n0  = blockIdx.x * 64;
    float* ob = out + (size_t)b * NF;

    for (int i = 0; i < 16; ++i) {
        int idx = (i * 256 + tid) * 4;
        int o = idx >> 7, k = idx & 127;
        float4 w = *(const float4*)(W + idx);
        half4 h;
        h[0] = (_Float16)w.x; h[1] = (_Float16)w.y;
        h[2] = (_Float16)w.z; h[3] = (_Float16)w.w;
        *(half4*)&sW[o * 136 + k] = h;
    }
    __syncthreads();

    const int wave = tid >> 6, lane = tid & 63;
    const int ln = lane & 15, quad = lane >> 4;
    const int nw = wave * 16;
    if (n0 + nw >= N_NODES) return;        // N_NODES % 16 == 0

    const _Float16* arow = ag + (size_t)(n0 + nw + ln) * BF + b * F;

    floatx4 acc[8];
    for (int ot = 0; ot < 8; ++ot) acc[ot] = (floatx4){0.f, 0.f, 0.f, 0.f};

    for (int k0 = 0; k0 < 4; ++k0) {
        half8 a = *(const half8*)(arow + k0 * 32 + quad * 8);
        for (int ot = 0; ot < 8; ++ot) {
            half8 bf = *(const half8*)&sW[(ot * 16 + ln) * 136 + k0 * 32 + quad * 8];
            acc[ot] = __builtin_amdgcn_mfma_f32_16x16x32_f16(a, bf, acc[ot], 0, 0, 0);
        }
    }

    float sv[4];
    for (int rg = 0; rg < 4; ++rg) sv[rg] = s[n0 + nw + quad * 4 + rg];
    for (int ot = 0; ot < 8; ++ot) {
        int o = ot * 16 + ln;
        float bo = bias[o];
        for (int rg = 0; rg < 4; ++rg) {
            int n = n0 + nw + quad * 4 + rg;
            float v = acc[ot][rg] + sv[rg] * bo;
            ob[(size_t)n * F + o] = fmaxf(v, 0.0f);
        }
    }
}

// ========== MFMA GEMM, A from fp32 out via LDS (fallback paths) =============
__global__ __launch_bounds__(256) void k_gemm1(const float* __restrict__ W,
                                               const float* __restrict__ bias,
                                               const float* __restrict__ s,
                                               float* __restrict__ out) {
    __shared__ _Float16 sW[128 * 136];
    __shared__ _Float16 sA[64 * 136];
    const int tid = threadIdx.x;
    const int b   = blockIdx.y;
    const int n0  = blockIdx.x * 64;
    float* ob = out + (size_t)b * NF;

    for (int i = 0; i < 16; ++i) {
        int idx = (i * 256 + tid) * 4;
        int o = idx >> 7, k = idx & 127;
        float4 w = *(const float4*)(W + idx);
        half4 h;
        h[0] = (_Float16)w.x; h[1] = (_Float16)w.y;
        h[2] = (_Float16)w.z; h[3] = (_Float16)w.w;
        *(half4*)&sW[o * 136 + k] = h;
    }
    for (int i = 0; i < 8; ++i) {
        int idx = (i * 256 + tid) * 4;
        int nl = idx >> 7, k = idx & 127;
        int n = n0 + nl;
        half4 h = {(_Float16)0.f, (_Float16)0.f, (_Float16)0.f, (_Float16)0.f};
        if (n < N_NODES) {
            float4 v = *(const float4*)(ob + (size_t)n * F + k);
            h[0] = (_Float16)v.x; h[1] = (_Float16)v.y;
            h[2] = (_Float16)v.z; h[3] = (_Float16)v.w;
        }
        *(half4*)&sA[nl * 136 + k] = h;
    }
    __syncthreads();

    const int wave = tid >> 6, lane = tid & 63;
    const int ln = lane & 15, quad = lane >> 4;
    const int nw = wave * 16;
    if (n0 + nw >= N_NODES) return;

    floatx4 acc[8];
    for (int ot = 0; ot < 8; ++ot) acc[ot] = (floatx4){0.f, 0.f, 0.f, 0.f};

    for (int k0 = 0; k0 < 4; ++k0) {
        half8 a = *(const half8*)&sA[(nw + ln) * 136 + k0 * 32 + quad * 8];
        for (int ot = 0; ot < 8; ++ot) {
            half8 bf = *(const half8*)&sW[(ot * 16 + ln) * 136 + k0 * 32 + quad * 8];
            acc[ot] = __builtin_amdgcn_mfma_f32_16x16x32_f16(a, bf, acc[ot], 0, 0, 0);
        }
    }

    float sv[4];
    for (int rg = 0; rg < 4; ++rg) sv[rg] = s[n0 + nw + quad * 4 + rg];
    for (int ot = 0; ot < 8; ++ot) {
        int o = ot * 16 + ln;
        float bo = bias[o];
        for (int rg = 0; rg < 4; ++rg) {
            int n = n0 + nw + quad * 4 + rg;
            float v = acc[ot][rg] + sv[rg] * bo;
            ob[(size_t)n * F + o] = fmaxf(v, 0.0f);
        }
    }
}

extern "C" void kernel_launch(void* const* d_in, const int* in_sizes, int n_in,
                              void* d_out, int out_size, void* d_ws, size_t ws_size,
                              hipStream_t stream) {
    const float* x    = (const float*)d_in[0];
    const int*   ei   = (const int*)d_in[1];
    const float* attr = (const float*)d_in[2];
    const float* W    = (const float*)d_in[3];
    const float* bias = (const float*)d_in[4];
    float* out = (float*)d_out;

    // ws layout: cnt[4N] | rofs[4N] | dinv[N] | s[N] | rowstart[N] | partials[256]
    //            | pad16 | sorted[E]*8B | xi[2NF]*2B | ag[2NF]*2B
    int*   cnt      = (int*)d_ws;
    int*   rofs     = cnt + 4 * N_NODES;
    float* dinv     = (float*)(rofs + 4 * N_NODES);
    float* s        = dinv + N_NODES;
    int*   rowstart = (int*)(s + N_NODES);
    int*   partials = rowstart + N_NODES;
    size_t sorted_off = ((size_t)((char*)(partials + 256) - (char*)d_ws) + 15) & ~(size_t)15;
    uint2* sorted   = (uint2*)((char*)d_ws + sorted_off);
    size_t xi_off   = sorted_off + (size_t)N_EDGES * 8;
    _Float16* xi    = (_Float16*)((char*)d_ws + xi_off);
    size_t ag_off   = xi_off + (size_t)2 * NF * 2;
    _Float16* ag    = (_Float16*)((char*)d_ws + ag_off);

    size_t need_T2 = xi_off;                       // CSR, fp32 gather
    size_t need_T0 = ag_off + (size_t)2 * NF * 2;  // + xi + ag fp16

    dim3 gg((N_NODES + 63) / 64, 2);
    size_t rthreads = (size_t)N_NODES * 64;
    unsigned rblocks = (unsigned)((rthreads + 255) / 256);

    if (ws_size >= need_T2) {
        hipMemsetAsync(cnt, 0, 4 * N_NODES * sizeof(int), stream);

        int do_cvt = (ws_size >= need_T0) ? 1 : 0;
        k_pre<<<PRE_BLOCKS, 256, 0, stream>>>(ei, cnt, x, xi, do_cvt);
        k_scan1<<<SCAN_BLOCKS, 256, 0, stream>>>(cnt, rowstart, rofs, partials);
        k_scan2<<<1, 256, 0, stream>>>(partials);
        k_fill<<<(N_EDGES + 255) / 256, 256, 0, stream>>>(ei, attr, rofs,
                                                          partials, cnt, sorted);
        k_deg_seg<<<rblocks, 256, 0, stream>>>(rowstart, partials, sorted, dinv);

        if (ws_size >= need_T0) {
            k_gather_h<<<rblocks, 256, 0, stream>>>(rowstart, partials, sorted,
                                                    xi, dinv, ag, s);
            k_gemm2<<<gg, 256, 0, stream>>>(ag, W, bias, s, out);
        } else {
            k_gather_f<<<rblocks, 256, 0, stream>>>(rowstart, partials, sorted,
                                                    x, dinv, out, s);
            k_gemm1<<<gg, 256, 0, stream>>>(W, bias, s, out);
        }
    } else {
        // atomic fallback: needs dinv[N]+s[N] only
        hipMemsetAsync(dinv, 0, N_NODES * sizeof(float), stream);
        hipMemsetAsync(s, 0, N_NODES * sizeof(float), stream);
        hipMemsetAsync(out, 0, (size_t)2 * NF * sizeof(float), stream);
        k_deg<<<(N_EDGES + 255) / 256, 256, 0, stream>>>(ei, attr, dinv);
        k_dinv<<<(N_NODES + 255) / 256, 256, 0, stream>>>(dinv);
        size_t edge_threads = (size_t)N_EDGES * 64;
        k_edge<<<(unsigned)((edge_threads + 255) / 256), 256, 0, stream>>>(
            ei, attr, dinv, x, out, s);
        k_self<<<(2 * NF / 4 + 255) / 256, 256, 0, stream>>>(x, dinv, out);
        k_sfix<<<(N_NODES + 255) / 256, 256, 0, stream>>>(dinv, s);
        k_gemm1<<<gg, 256, 0, stream>>>(W, bias, s, out);
    }
}

// Round 8
// 251.440 us; speedup vs baseline: 11.7587x; 1.0889x over previous
//
#include <hip/hip_runtime.h>

#define N_NODES 50000
#define N_EDGES 800000
#define F 128
#define BF 256
#define NF (N_NODES * F)
#define CAP 64                       // slots per node (max degree here ~40)
#define SPILL_CAP 131072
#define PRE_BLOCKS 3200
#define PRE_THREADS (PRE_BLOCKS * 256)

typedef __attribute__((ext_vector_type(8))) _Float16 half8;
typedef __attribute__((ext_vector_type(4))) _Float16 half4;
typedef __attribute__((ext_vector_type(4))) float floatx4;

// ========== build: one pass — slot-scatter edges + x -> fp16 interleaved ====
__global__ __launch_bounds__(256) void k_build(const int* __restrict__ ei,
                                               const float* __restrict__ attr,
                                               const float* __restrict__ x,
                                               int* __restrict__ cnt,       // [N+1], last = nspill
                                               uint4* __restrict__ spill,
                                               uint2* __restrict__ slots,   // [N][CAP]
                                               _Float16* __restrict__ xi) {
    int t = blockIdx.x * 256 + threadIdx.x;
    if (t < N_EDGES) {
        int r = ei[t];
        int c = ei[N_EDGES + t];
        float a = attr[t];
        int slot = atomicAdd(&cnt[r], 1);
        if (slot < CAP) {
            slots[(size_t)r * CAP + slot] = make_uint2((unsigned)c, __float_as_uint(a));
        } else {
            int sp = atomicAdd(&cnt[N_NODES], 1);
            if (sp < SPILL_CAP)
                spill[sp] = make_uint4((unsigned)r, (unsigned)c, __float_as_uint(a), 0u);
        }
    }
    // fused cvt: x[b][n][f] fp32 -> xi[n][b*128+f] fp16
    for (int i = t; i < 2 * NF / 4; i += PRE_THREADS) {
        size_t base = (size_t)i * 4;
        int b = (base >= (size_t)NF) ? 1 : 0;
        size_t rem = base - (size_t)b * NF;
        int n = (int)(rem >> 7);
        int f = (int)(rem & 127);
        float4 v = *(const float4*)(x + base);
        half4 h;
        h[0] = (_Float16)v.x; h[1] = (_Float16)v.y;
        h[2] = (_Float16)v.z; h[3] = (_Float16)v.w;
        *(half4*)(xi + (size_t)n * BF + b * F + f) = h;
    }
}

// ========== dinv[r] = rsqrt(1 + sum attr): one wave per row ================
__global__ __launch_bounds__(256) void k_deg_s(const int* __restrict__ cnt,
                                               const uint2* __restrict__ slots,
                                               const uint4* __restrict__ spill,
                                               float* __restrict__ dinv) {
    int r    = (int)(((size_t)blockIdx.x * 256 + threadIdx.x) >> 6);
    int lane = threadIdx.x & 63;
    if (r >= N_NODES) return;
    int cn = cnt[r];
    int m  = (cn < CAP) ? cn : CAP;
    float a = 0.0f;
    if (lane < m) a = __uint_as_float(slots[(size_t)r * CAP + lane].y);
    if (cn > CAP) {                       // spilled rows only
        int ns = cnt[N_NODES]; if (ns > SPILL_CAP) ns = SPILL_CAP;
        for (int i = lane; i < ns; i += 64) {
            uint4 e = spill[i];
            if ((int)e.x == r) a += __uint_as_float(e.z);
        }
    }
    for (int off = 32; off > 0; off >>= 1) a += __shfl_down(a, off);
    if (lane == 0) dinv[r] = rsqrtf(a + 1.0f);
}

// ========== gather -> fp16 ag (tier B): one wave per row ====================
__global__ __launch_bounds__(256) void k_gather_s(const int* __restrict__ cnt,
                                                  const uint2* __restrict__ slots,
                                                  const uint4* __restrict__ spill,
                                                  const _Float16* __restrict__ xi,
                                                  const float* __restrict__ dinv,
                                                  _Float16* __restrict__ ag,
                                                  float* __restrict__ s) {
    int r    = (int)(((size_t)blockIdx.x * 256 + threadIdx.x) >> 6);
    int lane = threadIdx.x & 63;
    if (r >= N_NODES) return;

    int cn = cnt[r];
    int m  = (cn < CAP) ? cn : CAP;
    int idx = lane * 4;

    int   ec = 0;
    float pw = 0.0f;
    if (lane < m) {
        uint2 en = slots[(size_t)r * CAP + lane];
        ec = (int)en.x;
        pw = __uint_as_float(en.y) * dinv[ec];
    }

    float dinvr = dinv[r];
    float nm0   = dinvr * dinvr;
    half4 hv    = *(const half4*)(xi + (size_t)r * BF + idx);

    float4 acc = make_float4(0.f, 0.f, 0.f, 0.f);
    float sp = 0.0f;
    for (int j = 0; j < m; ++j) {
        int   c = __shfl(ec, j);
        float p = __shfl(pw, j);
        half4 v = *(const half4*)(xi + (size_t)c * BF + idx);
        acc.x += p * (float)v[0]; acc.y += p * (float)v[1];
        acc.z += p * (float)v[2]; acc.w += p * (float)v[3];
        sp += p;
    }
    if (cn > CAP) {
        int ns = cnt[N_NODES]; if (ns > SPILL_CAP) ns = SPILL_CAP;
        for (int i = 0; i < ns; ++i) {
            uint4 e = spill[i];
            if ((int)e.x == r) {
                int c = (int)e.y;
                float p = __uint_as_float(e.z) * dinv[c];
                half4 v = *(const half4*)(xi + (size_t)c * BF + idx);
                acc.x += p * (float)v[0]; acc.y += p * (float)v[1];
                acc.z += p * (float)v[2]; acc.w += p * (float)v[3];
                sp += p;
            }
        }
    }

    half4 ho;
    ho[0] = (_Float16)(dinvr * acc.x + nm0 * (float)hv[0]);
    ho[1] = (_Float16)(dinvr * acc.y + nm0 * (float)hv[1]);
    ho[2] = (_Float16)(dinvr * acc.z + nm0 * (float)hv[2]);
    ho[3] = (_Float16)(dinvr * acc.w + nm0 * (float)hv[3]);
    *(half4*)(ag + (size_t)r * BF + idx) = ho;
    if (lane == 0) s[r] = dinvr * sp + nm0;
}

// ========== gather -> fp32 out (tier A, no ag buffer) =======================
__global__ __launch_bounds__(256) void k_gather_sf(const int* __restrict__ cnt,
                                                   const uint2* __restrict__ slots,
                                                   const uint4* __restrict__ spill,
                                                   const _Float16* __restrict__ xi,
                                                   const float* __restrict__ dinv,
                                                   float* __restrict__ out,
                                                   float* __restrict__ s) {
    int r    = (int)(((size_t)blockIdx.x * 256 + threadIdx.x) >> 6);
    int lane = threadIdx.x & 63;
    if (r >= N_NODES) return;

    int cn = cnt[r];
    int m  = (cn < CAP) ? cn : CAP;
    int idx = lane * 4;
    int b = idx >> 7;
    int f = idx & 127;

    int   ec = 0;
    float pw = 0.0f;
    if (lane < m) {
        uint2 en = slots[(size_t)r * CAP + lane];
        ec = (int)en.x;
        pw = __uint_as_float(en.y) * dinv[ec];
    }

    float dinvr = dinv[r];
    float nm0   = dinvr * dinvr;
    half4 hv    = *(const half4*)(xi + (size_t)r * BF + idx);

    float4 acc = make_float4(0.f, 0.f, 0.f, 0.f);
    float sp = 0.0f;
    for (int j = 0; j < m; ++j) {
        int   c = __shfl(ec, j);
        float p = __shfl(pw, j);
        half4 v = *(const half4*)(xi + (size_t)c * BF + idx);
        acc.x += p * (float)v[0]; acc.y += p * (float)v[1];
        acc.z += p * (float)v[2]; acc.w += p * (float)v[3];
        sp += p;
    }
    if (cn > CAP) {
        int ns = cnt[N_NODES]; if (ns > SPILL_CAP) ns = SPILL_CAP;
        for (int i = 0; i < ns; ++i) {
            uint4 e = spill[i];
            if ((int)e.x == r) {
                int c = (int)e.y;
                float p = __uint_as_float(e.z) * dinv[c];
                half4 v = *(const half4*)(xi + (size_t)c * BF + idx);
                acc.x += p * (float)v[0]; acc.y += p * (float)v[1];
                acc.z += p * (float)v[2]; acc.w += p * (float)v[3];
                sp += p;
            }
        }
    }

    float4 res = make_float4(dinvr * acc.x + nm0 * (float)hv[0],
                             dinvr * acc.y + nm0 * (float)hv[1],
                             dinvr * acc.z + nm0 * (float)hv[2],
                             dinvr * acc.w + nm0 * (float)hv[3]);
    *(float4*)(out + (size_t)b * NF + (size_t)r * F + f) = res;
    if (lane == 0) s[r] = dinvr * sp + nm0;
}

// ========== atomic fallback pieces (tiny ws) ================================
__global__ void k_deg(const int* __restrict__ ei, const float* __restrict__ attr,
                      float* __restrict__ deg) {
    int e = blockIdx.x * 256 + threadIdx.x;
    if (e < N_EDGES) atomicAdd(&deg[ei[e]], attr[e]);
}
__global__ void k_dinv(float* __restrict__ deg) {
    int n = blockIdx.x * 256 + threadIdx.x;
    if (n < N_NODES) deg[n] = rsqrtf(deg[n] + 1.0f);
}
__global__ __launch_bounds__(256) void k_edge(const int* __restrict__ ei,
                                              const float* __restrict__ attr,
                                              const float* __restrict__ dinv,
                                              const float* __restrict__ x,
                                              float* __restrict__ out,
                                              float* __restrict__ s) {
    int e    = (int)(((size_t)blockIdx.x * 256 + threadIdx.x) >> 6);
    int lane = threadIdx.x & 63;
    if (e >= N_EDGES) return;
    int r = ei[e];
    int c = ei[N_EDGES + e];
    float norm = dinv[r] * attr[e] * dinv[c];
    if (lane == 0) atomicAdd(&s[r], norm);
    int idx = lane * 4;
    int b = idx >> 7;
    int f = idx & 127;
    float4 v = *(const float4*)(x + (size_t)b * NF + (size_t)c * F + f);
    float* dst = out + (size_t)b * NF + (size_t)r * F + f;
    atomicAdd(dst + 0, norm * v.x);
    atomicAdd(dst + 1, norm * v.y);
    atomicAdd(dst + 2, norm * v.z);
    atomicAdd(dst + 3, norm * v.w);
}
__global__ void k_self(const float* __restrict__ x, const float* __restrict__ dinv,
                       float* __restrict__ out) {
    int i = blockIdx.x * 256 + threadIdx.x;
    if (i >= 2 * NF / 4) return;
    size_t base = (size_t)i * 4;
    int b = (base >= (size_t)NF) ? 1 : 0;
    size_t rem = base - (size_t)b * NF;
    int n = (int)(rem >> 7);
    float dn = dinv[n]; float sc = dn * dn;
    float4 v = *(const float4*)(x + base);
    float4* op = (float4*)(out + base);
    float4 o = *op;
    o.x += sc * v.x; o.y += sc * v.y; o.z += sc * v.z; o.w += sc * v.w;
    *op = o;
}
__global__ void k_sfix(const float* __restrict__ dinv, float* __restrict__ s) {
    int n = blockIdx.x * 256 + threadIdx.x;
    if (n < N_NODES) { float dn = dinv[n]; s[n] += dn * dn; }
}

// ========== MFMA GEMM, A direct from fp16 ag (tier B) =======================
__global__ __launch_bounds__(256) void k_gemm2(const _Float16* __restrict__ ag,
                                               const float* __restrict__ W,
                                               const float* __restrict__ bias,
                                               const float* __restrict__ s,
                                               float* __restrict__ out) {
    __shared__ _Float16 sW[128 * 136];
    const int tid = threadIdx.x;
    const int b   = blockIdx.y;
    const int n0  = blockIdx.x * 64;
    float* ob = out + (size_t)b * NF;

    for (int i = 0; i < 16; ++i) {
        int idx = (i * 256 + tid) * 4;
        int o = idx >> 7, k = idx & 127;
        float4 w = *(const float4*)(W + idx);
        half4 h;
        h[0] = (_Float16)w.x; h[1] = (_Float16)w.y;
        h[2] = (_Float16)w.z; h[3] = (_Float16)w.w;
        *(half4*)&sW[o * 136 + k] = h;
    }
    __syncthreads();

    const int wave = tid >> 6, lane = tid & 63;
    const int ln = lane & 15, quad = lane >> 4;
    const int nw = wave * 16;
    if (n0 + nw >= N_NODES) return;        // N_NODES % 16 == 0

    const _Float16* arow = ag + (size_t)(n0 + nw + ln) * BF + b * F;

    floatx4 acc[8];
    for (int ot = 0; ot < 8; ++ot) acc[ot] = (floatx4){0.f, 0.f, 0.f, 0.f};

    for (int k0 = 0; k0 < 4; ++k0) {
        half8 a = *(const half8*)(arow + k0 * 32 + quad * 8);
        for (int ot = 0; ot < 8; ++ot) {
            half8 bf = *(const half8*)&sW[(ot * 16 + ln) * 136 + k0 * 32 + quad * 8];
            acc[ot] = __builtin_amdgcn_mfma_f32_16x16x32_f16(a, bf, acc[ot], 0, 0, 0);
        }
    }

    float sv[4];
    for (int rg = 0; rg < 4; ++rg) sv[rg] = s[n0 + nw + quad * 4 + rg];
    for (int ot = 0; ot < 8; ++ot) {
        int o = ot * 16 + ln;
        float bo = bias[o];
        for (int rg = 0; rg < 4; ++rg) {
            int n = n0 + nw + quad * 4 + rg;
            float v = acc[ot][rg] + sv[rg] * bo;
            ob[(size_t)n * F + o] = fmaxf(v, 0.0f);
        }
    }
}

// ========== MFMA GEMM, A from fp32 out via LDS (tier A / fallback) ==========
__global__ __launch_bounds__(256) void k_gemm1(const float* __restrict__ W,
                                               const float* __restrict__ bias,
                                               const float* __restrict__ s,
                                               float* __restrict__ out) {
    __shared__ _Float16 sW[128 * 136];
    __shared__ _Float16 sA[64 * 136];
    const int tid = threadIdx.x;
    const int b   = blockIdx.y;
    const int n0  = blockIdx.x * 64;
    float* ob = out + (size_t)b * NF;

    for (int i = 0; i < 16; ++i) {
        int idx = (i * 256 + tid) * 4;
        int o = idx >> 7, k = idx & 127;
        float4 w = *(const float4*)(W + idx);
        half4 h;
        h[0] = (_Float16)w.x; h[1] = (_Float16)w.y;
        h[2] = (_Float16)w.z; h[3] = (_Float16)w.w;
        *(half4*)&sW[o * 136 + k] = h;
    }
    for (int i = 0; i < 8; ++i) {
        int idx = (i * 256 + tid) * 4;
        int nl = idx >> 7, k = idx & 127;
        int n = n0 + nl;
        half4 h = {(_Float16)0.f, (_Float16)0.f, (_Float16)0.f, (_Float16)0.f};
        if (n < N_NODES) {
            float4 v = *(const float4*)(ob + (size_t)n * F + k);
            h[0] = (_Float16)v.x; h[1] = (_Float16)v.y;
            h[2] = (_Float16)v.z; h[3] = (_Float16)v.w;
        }
        *(half4*)&sA[nl * 136 + k] = h;
    }
    __syncthreads();

    const int wave = tid >> 6, lane = tid & 63;
    const int ln = lane & 15, quad = lane >> 4;
    const int nw = wave * 16;
    if (n0 + nw >= N_NODES) return;

    floatx4 acc[8];
    for (int ot = 0; ot < 8; ++ot) acc[ot] = (floatx4){0.f, 0.f, 0.f, 0.f};

    for (int k0 = 0; k0 < 4; ++k0) {
        half8 a = *(const half8*)&sA[(nw + ln) * 136 + k0 * 32 + quad * 8];
        for (int ot = 0; ot < 8; ++ot) {
            half8 bf = *(const half8*)&sW[(ot * 16 + ln) * 136 + k0 * 32 + quad * 8];
            acc[ot] = __builtin_amdgcn_mfma_f32_16x16x32_f16(a, bf, acc[ot], 0, 0, 0);
        }
    }

    float sv[4];
    for (int rg = 0; rg < 4; ++rg) sv[rg] = s[n0 + nw + quad * 4 + rg];
    for (int ot = 0; ot < 8; ++ot) {
        int o = ot * 16 + ln;
        float bo = bias[o];
        for (int rg = 0; rg < 4; ++rg) {
            int n = n0 + nw + quad * 4 + rg;
            float v = acc[ot][rg] + sv[rg] * bo;
            ob[(size_t)n * F + o] = fmaxf(v, 0.0f);
        }
    }
}

extern "C" void kernel_launch(void* const* d_in, const int* in_sizes, int n_in,
                              void* d_out, int out_size, void* d_ws, size_t ws_size,
                              hipStream_t stream) {
    const float* x    = (const float*)d_in[0];
    const int*   ei   = (const int*)d_in[1];
    const float* attr = (const float*)d_in[2];
    const float* W    = (const float*)d_in[3];
    const float* bias = (const float*)d_in[4];
    float* out = (float*)d_out;

    // ws layout: cnt[N+1] | dinv[N] | s[N] | pad16 | spill[SPILL_CAP]*16B |
    //            slots[N*CAP]*8B | xi[2NF]*2B | ag[2NF]*2B (tier B only)
    int*   cnt  = (int*)d_ws;
    float* dinv = (float*)(cnt + N_NODES + 1);
    float* s    = dinv + N_NODES;
    size_t spill_off = ((size_t)((char*)(s + N_NODES) - (char*)d_ws) + 15) & ~(size_t)15;
    uint4* spill = (uint4*)((char*)d_ws + spill_off);
    size_t slots_off = spill_off + (size_t)SPILL_CAP * 16;
    uint2* slots = (uint2*)((char*)d_ws + slots_off);
    size_t xi_off = slots_off + (size_t)N_NODES * CAP * 8;
    _Float16* xi = (_Float16*)((char*)d_ws + xi_off);
    size_t ag_off = xi_off + (size_t)2 * NF * 2;
    _Float16* ag = (_Float16*)((char*)d_ws + ag_off);

    size_t need_A = ag_off;                        // slotted, gather -> fp32 out
    size_t need_B = ag_off + (size_t)2 * NF * 2;   // + fp16 ag

    dim3 gg((N_NODES + 63) / 64, 2);
    size_t rthreads = (size_t)N_NODES * 64;
    unsigned rblocks = (unsigned)((rthreads + 255) / 256);

    if (ws_size >= need_A) {
        hipMemsetAsync(cnt, 0, (N_NODES + 1) * sizeof(int), stream);
        k_build<<<PRE_BLOCKS, 256, 0, stream>>>(ei, attr, x, cnt, spill, slots, xi);
        k_deg_s<<<rblocks, 256, 0, stream>>>(cnt, slots, spill, dinv);
        if (ws_size >= need_B) {
            k_gather_s<<<rblocks, 256, 0, stream>>>(cnt, slots, spill, xi, dinv, ag, s);
            k_gemm2<<<gg, 256, 0, stream>>>(ag, W, bias, s, out);
        } else {
            k_gather_sf<<<rblocks, 256, 0, stream>>>(cnt, slots, spill, xi, dinv, out, s);
            k_gemm1<<<gg, 256, 0, stream>>>(W, bias, s, out);
        }
    } else {
        // atomic fallback: needs dinv[N]+s[N] only
        hipMemsetAsync(dinv, 0, N_NODES * sizeof(float), stream);
        hipMemsetAsync(s, 0, N_NODES * sizeof(float), stream);
        hipMemsetAsync(out, 0, (size_t)2 * NF * sizeof(float), stream);
        k_deg<<<(N_EDGES + 255) / 256, 256, 0, stream>>>(ei, attr, dinv);
        k_dinv<<<(N_NODES + 255) / 256, 256, 0, stream>>>(dinv);
        size_t edge_threads = (size_t)N_EDGES * 64;
        k_edge<<<(unsigned)((edge_threads + 255) / 256), 256, 0, stream>>>(
            ei, attr, dinv, x, out, s);
        k_self<<<(2 * NF / 4 + 255) / 256, 256, 0, stream>>>(x, dinv, out);
        k_sfix<<<(N_NODES + 255) / 256, 256, 0, stream>>>(dinv, s);
        k_gemm1<<<gg, 256, 0, stream>>>(W, bias, s, out);
    }
}